// Round 2
// baseline (3019.981 us; speedup 1.0000x reference)
//
#include <hip/hip_runtime.h>
#include <math.h>

// ---------------------------------------------------------------------------
// Encoder_75557064671564 — pipeline with bf16 intermediates (fp32 accumulate).
// Workspace budget: 2 x bf16 x-tensors (64 MB each) + fp32 low-pass buffers
// + tables = ~143.6 MB total (round-1 fp32 layout was 268.6 MB -> OOB fault).
//
//   low_pass:  row-DFT (101 surviving cols) -> per-column Dirichlet circulant
//              -> row-IDFT + floor/clip/255.  Double accumulators (floor is
//              flip-sensitive); fp32 tables.
//   conv stack: direct fp32-accum conv3x3 from bf16 inputs, BN stats via
//              partials (+double finalize), normalize+relu fused into the
//              NEXT conv's LDS staging. Biases skipped (cancel under BN).
//   watermark: fft2/ifft2 replaced by 30 direct DFT coefficients + sparse
//              30-term per-pixel correction on channel 0 only.
//   conv5:     concat(msg,enc,image) synthesized in the tile loader.
// ---------------------------------------------------------------------------

#define NPX 65536          // 256*256
// watermark positions (replicates reference loop enumeration; all chan 0)
__constant__ int WM_R_[30] = {124, 125,125,125,125,125, 126,126,126,126,126,126,126,
                              127,127,127,127,127,127,127,
                              128,128,128,128,128,128,128,128,128, 129};
__constant__ int WM_C_[30] = {128, 126,127,128,129,130, 125,126,127,128,129,130,131,
                              125,126,127,128,129,130,131,
                              124,125,126,127,128,129,130,131,132, 125};

__device__ __forceinline__ float bfu2f(unsigned int bits) {
    return __uint_as_float(bits << 16);
}
__device__ __forceinline__ unsigned short f2bu(float f) {
    unsigned int u = __float_as_uint(f);
    u += 0x7fffu + ((u >> 16) & 1u);   // round-to-nearest-even
    return (unsigned short)(u >> 16);
}

// twiddle table tw[0..255]=cos(-2pi t/256), tw[256..511]=sin(-2pi t/256)
// d2t[d][kxi] : Dirichlet kernel (incl 1/256) for column kxi, lag d
__global__ void k_tables(float* __restrict__ tw, float* __restrict__ d2t) {
    int idx = blockIdx.x * 256 + threadIdx.x;
    if (idx < 256) {
        double ang = -2.0 * M_PI * (double)idx / 256.0;
        tw[idx]       = (float)cos(ang);
        tw[256 + idx] = (float)sin(ang);
    }
    int q = idx - 256;
    if (q >= 0 && q < 256 * 101) {
        int d = q / 101, kxi = q - d * 101;
        int vx = (kxi <= 50) ? kxi : kxi - 101;
        int r2 = 2500 - vx * vx;
        int L = 0;
        while ((L + 1) * (L + 1) <= r2) L++;
        double s = 1.0;
        for (int v = 1; v <= L; v++) s += 2.0 * cos(2.0 * M_PI * (double)(v * d) / 256.0);
        d2t[d * 101 + kxi] = (float)(s / 256.0);
    }
}

// row forward DFT, keep 101 cols. Y[ch][y][kxi][2]
__global__ void k_lp1(const float* __restrict__ img, const float* __restrict__ tw,
                      float* __restrict__ Y) {
    __shared__ float row[256];
    __shared__ float twl[512];
    int y = blockIdx.x, ch = blockIdx.y, tid = threadIdx.x; // 128 threads
    row[tid]       = img[ch * NPX + y * 256 + tid];
    row[tid + 128] = img[ch * NPX + y * 256 + tid + 128];
    twl[tid] = tw[tid]; twl[tid+128] = tw[tid+128];
    twl[tid+256] = tw[tid+256]; twl[tid+384] = tw[tid+384];
    __syncthreads();
    if (tid < 101) {
        int kx = (tid <= 50) ? tid : tid + 155;
        double ar = 0.0, ai = 0.0;
        for (int x = 0; x < 256; x++) {
            int t = (kx * x) & 255;
            double v = (double)row[x];
            ar += v * (double)twl[t];
            ai += v * (double)twl[256 + t];
        }
        int o = ((ch * 256 + y) * 101 + tid) * 2;
        Y[o] = (float)ar; Y[o + 1] = (float)ai;
    }
}

// per-column circulant (masked col fft+ifft collapsed). W[ch][y][kxi][2]
__global__ void k_lp2(const float* __restrict__ Y, const float* __restrict__ d2t,
                      float* __restrict__ W) {
    int y = blockIdx.x, ch = blockIdx.y, kxi = threadIdx.x; // 128 threads
    if (kxi >= 101) return;
    const float* Yc = Y + ch * 256 * 101 * 2;
    double ar = 0.0, ai = 0.0;
    for (int yp = 0; yp < 256; yp++) {
        int d = (y - yp) & 255;
        double Dv = (double)d2t[d * 101 + kxi];
        ar += Dv * (double)Yc[(yp * 101 + kxi) * 2];
        ai += Dv * (double)Yc[(yp * 101 + kxi) * 2 + 1];
    }
    int o = ((ch * 256 + y) * 101 + kxi) * 2;
    W[o] = (float)ar; W[o + 1] = (float)ai;
}

// row inverse DFT + clip/floor/255
__global__ void k_lp3(const float* __restrict__ W, const float* __restrict__ tw,
                      float* __restrict__ lp) {
    __shared__ float wr[101], wi[101];
    __shared__ float twl[512];
    int y = blockIdx.x, ch = blockIdx.y, x = threadIdx.x; // 256 threads
    if (x < 101) {
        wr[x] = W[((ch * 256 + y) * 101 + x) * 2];
        wi[x] = W[((ch * 256 + y) * 101 + x) * 2 + 1];
    }
    twl[x] = tw[x]; twl[x + 256] = tw[x + 256];
    __syncthreads();
    double acc = 0.0;
    for (int kxi = 0; kxi < 101; kxi++) {
        int kx = (kxi <= 50) ? kxi : kxi + 155;
        int t = (kx * x) & 255;
        // e^{+i 2pi kx x/256}: Re(W * e) = Wre*cos + Wim*sin_neg
        acc += (double)wr[kxi] * (double)twl[t] + (double)wi[kxi] * (double)twl[256 + t];
    }
    acc *= (1.0 / 256.0);
    acc = floor(fmin(fmax(acc, 0.0), 255.0)) / 255.0;
    lp[ch * NPX + y * 256 + x] = (float)acc;
}

// direct conv3x3, pad 1, 64 out channels, bf16 output.
// MODE 0: fp32 input inF [B][CIN][H][W] (the lp buffer)
// MODE 1: bf16 input inH, relu(v*s+t) fused on load
// MODE 2: concat(msg[30] fp32, enc[64] bf16 (already final), img[3] fp32)
template <int MODE>
__global__ __launch_bounds__(256, 2) void k_conv(
    const unsigned short* __restrict__ inH, const float* __restrict__ inF,
    const float* __restrict__ wgt, const float* __restrict__ st,
    const float* __restrict__ msg, const float* __restrict__ img,
    unsigned short* __restrict__ out, int CIN) {
    __shared__ float wl[16][9][64];   // [ic'][tap][oc]
    __shared__ float al[16][18][18];  // [ic'][y][x]
    int tid = threadIdx.x;
    int b = blockIdx.z, r0 = blockIdx.y * 16, c0 = blockIdx.x * 16;
    int ocg = tid >> 5, pxg = tid & 31;
    int row = pxg >> 1, chof = (pxg & 1) * 8;
    int oc0 = ocg * 8;
    float acc[8][8];
#pragma unroll
    for (int o = 0; o < 8; o++) {
#pragma unroll
        for (int p = 0; p < 8; p++) acc[o][p] = 0.f;
    }
    for (int icc = 0; icc < CIN; icc += 16) {
        int icn = min(16, CIN - icc);
        __syncthreads();
        // stage weights [oc][CIN][3][3] -> wl[ic'][tap][oc]
        for (int idx = tid; idx < icn * 576; idx += 256) {
            int ic = idx / 576, rem = idx - ic * 576;
            int tap = rem >> 6, oc = rem & 63;
            wl[ic][tap][oc] = wgt[(oc * CIN + icc + ic) * 9 + tap];
        }
        // stage input tile (18x18 halo), zero-padded
        for (int idx = tid; idx < icn * 324; idx += 256) {
            int ic = idx / 324, rem = idx - ic * 324;
            int ly = rem / 18, lx = rem - ly * 18;
            int gy = r0 - 1 + ly, gx = c0 - 1 + lx;
            float v = 0.f;
            if ((unsigned)gy < 256u && (unsigned)gx < 256u) {
                int gc = icc + ic;
                if (MODE == 2) {
                    if (gc < 30)      v = msg[b * 30 + gc];
                    else if (gc < 94) v = bfu2f(inH[(b * 64 + (gc - 30)) * NPX + gy * 256 + gx]);
                    else              v = img[(b * 3 + (gc - 94)) * NPX + gy * 256 + gx];
                } else if (MODE == 1) {
                    v = bfu2f(inH[(b * CIN + gc) * NPX + gy * 256 + gx]);
                    v = fmaxf(v * st[gc * 2] + st[gc * 2 + 1], 0.f);
                } else {
                    v = inF[(b * CIN + gc) * NPX + gy * 256 + gx];
                }
            }
            al[ic][ly][lx] = v;
        }
        __syncthreads();
        for (int ic = 0; ic < icn; ic++) {
            float areg[3][10];
#pragma unroll
            for (int di = 0; di < 3; di++) {
#pragma unroll
                for (int xx = 0; xx < 10; xx++) areg[di][xx] = al[ic][row + di][chof + xx];
            }
#pragma unroll
            for (int tap = 0; tap < 9; tap++) {
                const int di = tap / 3, dj = tap % 3;
                float wv[8];
#pragma unroll
                for (int o = 0; o < 8; o++) wv[o] = wl[ic][tap][oc0 + o];
#pragma unroll
                for (int o = 0; o < 8; o++) {
#pragma unroll
                    for (int p = 0; p < 8; p++)
                        acc[o][p] = fmaf(wv[o], areg[di][dj + p], acc[o][p]);
                }
            }
        }
    }
#pragma unroll
    for (int o = 0; o < 8; o++) {
        unsigned int pk[4];
#pragma unroll
        for (int q = 0; q < 4; q++) {
            pk[q] = (unsigned int)f2bu(acc[o][2 * q]) |
                    ((unsigned int)f2bu(acc[o][2 * q + 1]) << 16);
        }
        unsigned short* op = out + (size_t)(b * 64 + oc0 + o) * NPX + (r0 + row) * 256 + (c0 + chof);
        uint4 vv; vv.x = pk[0]; vv.y = pk[1]; vv.z = pk[2]; vv.w = pk[3];
        *reinterpret_cast<uint4*>(op) = vv;
    }
}

// per-channel partial sums over raw conv output (bf16). part[c][blk][2]
__global__ void k_stats(const unsigned short* __restrict__ y, float* __restrict__ part) {
    __shared__ float s1s[256], s2s[256];
    int c = blockIdx.x, blk = blockIdx.y, tid = threadIdx.x;
    float s1 = 0.f, s2 = 0.f;
    for (int it = 0; it < 4; it++) {
        int e = blk * 8192 + it * 2048 + tid * 8;   // < 524288, 8-aligned
        int b = e >> 16, px = e & 65535;
        const uint4* p = reinterpret_cast<const uint4*>(y + (size_t)(b * 64 + c) * NPX + px);
        uint4 u = *p;
        unsigned int wd[4] = {u.x, u.y, u.z, u.w};
#pragma unroll
        for (int q = 0; q < 4; q++) {
            float v0 = bfu2f(wd[q] & 0xffffu);
            float v1 = bfu2f(wd[q] >> 16);
            s1 += v0 + v1; s2 += v0 * v0 + v1 * v1;
        }
    }
    s1s[tid] = s1; s2s[tid] = s2;
    __syncthreads();
    for (int s = 128; s > 0; s >>= 1) {
        if (tid < s) { s1s[tid] += s1s[tid + s]; s2s[tid] += s2s[tid + s]; }
        __syncthreads();
    }
    if (tid == 0) {
        part[(c * 64 + blk) * 2]     = s1s[0];
        part[(c * 64 + blk) * 2 + 1] = s2s[0];
    }
}

// st[c] = (scale, shift):  relu(y*s+t) == relu((y-mean)*rsqrt(var+eps)*g + be)
__global__ void k_finalize(const float* __restrict__ part, const float* __restrict__ g,
                           const float* __restrict__ be, float* __restrict__ st) {
    int c = threadIdx.x;
    if (c >= 64) return;
    double S1 = 0.0, S2 = 0.0;
    for (int k = 0; k < 64; k++) {
        S1 += (double)part[(c * 64 + k) * 2];
        S2 += (double)part[(c * 64 + k) * 2 + 1];
    }
    const double Nn = 524288.0;
    double mean = S1 / Nn;
    double var = S2 / Nn - mean * mean;
    float s = (float)((double)g[c] / sqrt(var + 1e-5));
    float t = (float)((double)be[c] - mean * (double)s);
    st[c * 2] = s; st[c * 2 + 1] = t;
}

// 30 DFT coefficients of x4 channel 0 -> delta = (m + i m) - F
__global__ void k_fcoef(const unsigned short* __restrict__ y4, const float* __restrict__ st,
                        const float* __restrict__ msg, const float* __restrict__ tw,
                        float* __restrict__ dlt) {
    __shared__ float twl[512];
    __shared__ float rr[256], ri[256];
    int p = blockIdx.x, b = blockIdx.y, tid = threadIdx.x; // 256 threads
    twl[tid] = tw[tid]; twl[tid + 256] = tw[tid + 256];
    __syncthreads();
    int r = WM_R_[p], c = WM_C_[p];
    float s0 = st[0], t0 = st[1];
    float ar = 0.f, ai = 0.f;
    for (int k = 0; k < 256; k++) {        // y = k, x = tid
        float v = fmaxf(bfu2f(y4[(size_t)(b * 64) * NPX + k * 256 + tid]) * s0 + t0, 0.f);
        int t = (r * k + c * tid) & 255;
        ar += v * twl[t];
        ai += v * twl[256 + t];
    }
    rr[tid] = ar; ri[tid] = ai;
    __syncthreads();
    for (int s = 128; s > 0; s >>= 1) {
        if (tid < s) { rr[tid] += rr[tid + s]; ri[tid] += ri[tid + s]; }
        __syncthreads();
    }
    if (tid == 0) {
        float m = msg[b * 30 + p];
        dlt[(b * 30 + p) * 2]     = m - rr[0];
        dlt[(b * 30 + p) * 2 + 1] = m - ri[0];
    }
}

// enc = relu(y4*s+t); channel 0 += (1/N^2) Re( sum_p delta_p e^{+i...} )
__global__ void k_enc(const unsigned short* __restrict__ y4, const float* __restrict__ st,
                      const float* __restrict__ dlt, const float* __restrict__ tw,
                      unsigned short* __restrict__ enc) {
    int y = blockIdx.x, c = blockIdx.y, b = blockIdx.z, x = threadIdx.x;
    float v = fmaxf(bfu2f(y4[(size_t)(b * 64 + c) * NPX + y * 256 + x]) * st[c * 2] + st[c * 2 + 1], 0.f);
    if (c == 0) {  // uniform per block
        __shared__ float dr[30], di[30];
        __shared__ float twl[512];
        if (x < 30) { dr[x] = dlt[(b * 30 + x) * 2]; di[x] = dlt[(b * 30 + x) * 2 + 1]; }
        twl[x] = tw[x]; twl[x + 256] = tw[x + 256];
        __syncthreads();
        float corr = 0.f;
#pragma unroll
        for (int p = 0; p < 30; p++) {
            int t = (WM_R_[p] * y + WM_C_[p] * x) & 255;
            corr += dr[p] * twl[t] + di[p] * twl[256 + t];
        }
        v += corr * (1.0f / 65536.0f);
    }
    enc[(size_t)(b * 64 + c) * NPX + y * 256 + x] = f2bu(v);
}

// final 1x1 conv (with bias), input BN transform fused
__global__ void k_final(const unsigned short* __restrict__ y5, const float* __restrict__ st,
                        const float* __restrict__ fw, const float* __restrict__ fb,
                        float* __restrict__ out) {
    __shared__ float fwl[3][64];
    __shared__ float sl[64], tl[64];
    __shared__ float fbl[3];
    int tid = threadIdx.x;
    if (tid < 192) fwl[tid / 64][tid & 63] = fw[tid];
    if (tid < 64) { sl[tid] = st[tid * 2]; tl[tid] = st[tid * 2 + 1]; }
    if (tid < 3) fbl[tid] = fb[tid];
    __syncthreads();
    int e = blockIdx.x * 256 + tid;  // < 524288
    int b = e >> 16, px = e & 65535;
    float a0 = fbl[0], a1 = fbl[1], a2 = fbl[2];
    for (int c = 0; c < 64; c++) {
        float v = fmaxf(bfu2f(y5[(size_t)(b * 64 + c) * NPX + px]) * sl[c] + tl[c], 0.f);
        a0 = fmaf(v, fwl[0][c], a0);
        a1 = fmaf(v, fwl[1][c], a1);
        a2 = fmaf(v, fwl[2][c], a2);
    }
    out[(b * 3 + 0) * NPX + px] = a0;
    out[(b * 3 + 1) * NPX + px] = a1;
    out[(b * 3 + 2) * NPX + px] = a2;
}

extern "C" void kernel_launch(void* const* d_in, const int* in_sizes, int n_in,
                              void* d_out, int out_size, void* d_ws, size_t ws_size,
                              hipStream_t stream) {
    (void)in_sizes; (void)n_in; (void)out_size; (void)ws_size;
    const float* image   = (const float*)d_in[0];
    const float* message = (const float*)d_in[1];
    const float* w0      = (const float*)d_in[2];
    const float* g0      = (const float*)d_in[4];
    const float* be0     = (const float*)d_in[5];
    const float* wsv     = (const float*)d_in[6];
    const float* gs      = (const float*)d_in[8];
    const float* bes     = (const float*)d_in[9];
    const float* acw     = (const float*)d_in[10];
    const float* acg     = (const float*)d_in[12];
    const float* acbe    = (const float*)d_in[13];
    const float* fw      = (const float*)d_in[14];
    const float* fb      = (const float*)d_in[15];
    float* out = (float*)d_out;

    // workspace layout — total 150,578,560 bytes (~143.6 MB)
    unsigned short* XA = (unsigned short*)d_ws;   // 33,554,432 bf16 (64 MB)
    unsigned short* XB = XA + 33554432;           // 33,554,432 bf16 (64 MB)
    float* TW   = (float*)(XB + 33554432);        // 512 f
    float* D2T  = TW + 512;                       // 25,856 f
    float* PART = D2T + 25856;                    // 8,192 f
    float* ST   = PART + 8192;                    // 128 f
    float* DLT  = ST + 128;                       // 480 f
    float* Yb   = DLT + 480;                      // 1,241,088 f
    float* Wb   = Yb + 1241088;                   // 1,241,088 f
    float* LP   = Wb + 1241088;                   // 1,572,864 f

    // tables
    k_tables<<<103, 256, 0, stream>>>(TW, D2T);
    // low-pass filter: image -> LP
    k_lp1<<<dim3(256, 24), 128, 0, stream>>>(image, TW, Yb);
    k_lp2<<<dim3(256, 24), 128, 0, stream>>>(Yb, D2T, Wb);
    k_lp3<<<dim3(256, 24), 256, 0, stream>>>(Wb, TW, LP);

    dim3 cgrid(16, 16, 8), sgrid(64, 64);
    // conv1: lp -> XA (raw bf16), stats
    k_conv<0><<<cgrid, 256, 0, stream>>>(nullptr, LP, w0, nullptr, nullptr, nullptr, XA, 3);
    k_stats<<<sgrid, 256, 0, stream>>>(XA, PART);
    k_finalize<<<1, 64, 0, stream>>>(PART, g0, be0, ST);
    // conv2: XA -> XB
    k_conv<1><<<cgrid, 256, 0, stream>>>(XA, nullptr, wsv + 0 * 36864, ST, nullptr, nullptr, XB, 64);
    k_stats<<<sgrid, 256, 0, stream>>>(XB, PART);
    k_finalize<<<1, 64, 0, stream>>>(PART, gs + 0, bes + 0, ST);
    // conv3: XB -> XA
    k_conv<1><<<cgrid, 256, 0, stream>>>(XB, nullptr, wsv + 1 * 36864, ST, nullptr, nullptr, XA, 64);
    k_stats<<<sgrid, 256, 0, stream>>>(XA, PART);
    k_finalize<<<1, 64, 0, stream>>>(PART, gs + 64, bes + 64, ST);
    // conv4: XA -> XB (raw y4)
    k_conv<1><<<cgrid, 256, 0, stream>>>(XA, nullptr, wsv + 2 * 36864, ST, nullptr, nullptr, XB, 64);
    k_stats<<<sgrid, 256, 0, stream>>>(XB, PART);
    k_finalize<<<1, 64, 0, stream>>>(PART, gs + 128, bes + 128, ST);
    // watermark: 30 DFT coefficients of x4 ch0, then materialize enc -> XA
    k_fcoef<<<dim3(30, 8), 256, 0, stream>>>(XB, ST, message, TW, DLT);
    k_enc<<<dim3(256, 64, 8), 256, 0, stream>>>(XB, ST, DLT, TW, XA);
    // conv5 (concat msg|enc|image): -> XB
    k_conv<2><<<cgrid, 256, 0, stream>>>(XA, nullptr, acw, nullptr, message, image, XB, 97);
    k_stats<<<sgrid, 256, 0, stream>>>(XB, PART);
    k_finalize<<<1, 64, 0, stream>>>(PART, acg, acbe, ST);
    // final 1x1 conv -> out
    k_final<<<2048, 256, 0, stream>>>(XB, ST, fw, fb, out);
}

// Round 4
// 921.091 us; speedup vs baseline: 3.2787x; 3.2787x over previous
//
#include <hip/hip_runtime.h>
#include <math.h>

// ---------------------------------------------------------------------------
// Encoder_75557064671564 — MFMA bf16 conv stack, NHWC intermediates.
//
// ROUND-4 FIX: workspace overflow. Round-3 layout was 151,194,496 B; if
// ws_size == 144 MiB (150,994,944 B) the LP tail OOB-wrote into the adjacent
// allocation (pristine input copies) -> call 1 valid, calls 2+ corrupted.
// Low-pass scratch (Yb/Wb/LP) now aliases XB (first written by conv2, after
// LP is consumed by conv1). Total: 134,974,336 B (~128.7 MiB).
//
//   low_pass:  row-DFT (101 surviving cols) -> per-column Dirichlet circulant
//              -> row-IDFT + floor/clip/255 (double accumulators).
//   conv1:     VALU fp32 (CIN=3), NHWC bf16 raw output.
//   conv2-5:   implicit-GEMM 3x3 conv via v_mfma_f32_16x16x32_bf16.
//   watermark: 30 DFT coeffs via row-DFT(6 rows)+col pass; correction and
//              BN+relu fused into conv5 staging (enc never materialized).
//   conv5 msg channels: spatially constant -> per-(b,oc,border-class)
//              additive term, removed from GEMM.
// ---------------------------------------------------------------------------

#define NPX 65536
typedef unsigned short u16;
typedef __bf16 bfrag_t __attribute__((ext_vector_type(8)));
typedef float f32x4 __attribute__((ext_vector_type(4)));

__constant__ int WM_R_[30] = {124, 125,125,125,125,125, 126,126,126,126,126,126,126,
                              127,127,127,127,127,127,127,
                              128,128,128,128,128,128,128,128,128, 129};
__constant__ int WM_C_[30] = {128, 126,127,128,129,130, 125,126,127,128,129,130,131,
                              125,126,127,128,129,130,131,
                              124,125,126,127,128,129,130,131,132, 125};

__device__ __forceinline__ float bfu2f(unsigned int bits) {
    return __uint_as_float(bits << 16);
}
__device__ __forceinline__ u16 f2bu(float f) {
    unsigned int u = __float_as_uint(f);
    u += 0x7fffu + ((u >> 16) & 1u);
    return (u16)(u >> 16);
}

// ---------------- tables ----------------
__global__ void k_tables(float* __restrict__ tw, float* __restrict__ d2t) {
    int idx = blockIdx.x * 256 + threadIdx.x;
    if (idx < 256) {
        double ang = -2.0 * M_PI * (double)idx / 256.0;
        tw[idx]       = (float)cos(ang);
        tw[256 + idx] = (float)sin(ang);
    }
    int q = idx - 256;
    if (q >= 0 && q < 256 * 101) {
        int d = q / 101, kxi = q - d * 101;
        int vx = (kxi <= 50) ? kxi : kxi - 101;
        int r2 = 2500 - vx * vx;
        int L = 0;
        while ((L + 1) * (L + 1) <= r2) L++;
        double s = 1.0;
        for (int v = 1; v <= L; v++) s += 2.0 * cos(2.0 * M_PI * (double)(v * d) / 256.0);
        d2t[d * 101 + kxi] = (float)(s / 256.0);
    }
}

// ---------------- low-pass chain ----------------
__global__ void k_lp1(const float* __restrict__ img, const float* __restrict__ tw,
                      float* __restrict__ Y) {
    __shared__ float row[256];
    __shared__ float twl[512];
    int y = blockIdx.x, ch = blockIdx.y, tid = threadIdx.x; // 128 threads
    row[tid]       = img[ch * NPX + y * 256 + tid];
    row[tid + 128] = img[ch * NPX + y * 256 + tid + 128];
    twl[tid] = tw[tid]; twl[tid+128] = tw[tid+128];
    twl[tid+256] = tw[tid+256]; twl[tid+384] = tw[tid+384];
    __syncthreads();
    if (tid < 101) {
        int kx = (tid <= 50) ? tid : tid + 155;
        double ar = 0.0, ai = 0.0;
        for (int x = 0; x < 256; x++) {
            int t = (kx * x) & 255;
            double v = (double)row[x];
            ar += v * (double)twl[t];
            ai += v * (double)twl[256 + t];
        }
        int o = ((ch * 256 + y) * 101 + tid) * 2;
        Y[o] = (float)ar; Y[o + 1] = (float)ai;
    }
}

__global__ void k_lp2(const float* __restrict__ Y, const float* __restrict__ d2t,
                      float* __restrict__ W) {
    int y = blockIdx.x, ch = blockIdx.y, kxi = threadIdx.x; // 128 threads
    if (kxi >= 101) return;
    const float* Yc = Y + ch * 256 * 101 * 2;
    double ar = 0.0, ai = 0.0;
    for (int yp = 0; yp < 256; yp++) {
        int d = (y - yp) & 255;
        double Dv = (double)d2t[d * 101 + kxi];
        ar += Dv * (double)Yc[(yp * 101 + kxi) * 2];
        ai += Dv * (double)Yc[(yp * 101 + kxi) * 2 + 1];
    }
    int o = ((ch * 256 + y) * 101 + kxi) * 2;
    W[o] = (float)ar; W[o + 1] = (float)ai;
}

__global__ void k_lp3(const float* __restrict__ W, const float* __restrict__ tw,
                      float* __restrict__ lp) {
    __shared__ float wr[101], wi[101];
    __shared__ float twl[512];
    int y = blockIdx.x, ch = blockIdx.y, x = threadIdx.x; // 256 threads
    if (x < 101) {
        wr[x] = W[((ch * 256 + y) * 101 + x) * 2];
        wi[x] = W[((ch * 256 + y) * 101 + x) * 2 + 1];
    }
    twl[x] = tw[x]; twl[x + 256] = tw[x + 256];
    __syncthreads();
    double acc = 0.0;
    for (int kxi = 0; kxi < 101; kxi++) {
        int kx = (kxi <= 50) ? kxi : kxi + 155;
        int t = (kx * x) & 255;
        acc += (double)wr[kxi] * (double)twl[t] + (double)wi[kxi] * (double)twl[256 + t];
    }
    acc *= (1.0 / 256.0);
    acc = floor(fmin(fmax(acc, 0.0), 255.0)) / 255.0;
    lp[ch * NPX + y * 256 + x] = (float)acc;
}

// ---------------- conv1: CIN=3, fp32 VALU, NHWC bf16 out ----------------
__global__ __launch_bounds__(256, 2) void k_conv1(
    const float* __restrict__ lp, const float* __restrict__ w0,
    u16* __restrict__ out) {
    __shared__ float wl[3][9][64];
    __shared__ float al[3][18][18];
    int tid = threadIdx.x;
    int b = blockIdx.z, r0 = blockIdx.y * 16, c0 = blockIdx.x * 16;
    int ocg = tid >> 5, pxg = tid & 31;
    int row = pxg >> 1, chof = (pxg & 1) * 8;
    int oc0 = ocg * 8;
    float acc[8][8];
#pragma unroll
    for (int o = 0; o < 8; o++)
#pragma unroll
        for (int p = 0; p < 8; p++) acc[o][p] = 0.f;
    for (int idx = tid; idx < 1728; idx += 256) {
        int ic = idx / 576, rem = idx - ic * 576;
        int tap = rem >> 6, oc = rem & 63;
        wl[ic][tap][oc] = w0[(oc * 3 + ic) * 9 + tap];
    }
    for (int idx = tid; idx < 972; idx += 256) {
        int ic = idx / 324, rem = idx - ic * 324;
        int ly = rem / 18, lx = rem - ly * 18;
        int gy = r0 - 1 + ly, gx = c0 - 1 + lx;
        float v = 0.f;
        if ((unsigned)gy < 256u && (unsigned)gx < 256u)
            v = lp[(b * 3 + ic) * NPX + gy * 256 + gx];
        al[ic][ly][lx] = v;
    }
    __syncthreads();
    for (int ic = 0; ic < 3; ic++) {
        float areg[3][10];
#pragma unroll
        for (int di = 0; di < 3; di++)
#pragma unroll
            for (int xx = 0; xx < 10; xx++) areg[di][xx] = al[ic][row + di][chof + xx];
#pragma unroll
        for (int tap = 0; tap < 9; tap++) {
            const int di = tap / 3, dj = tap % 3;
            float wv[8];
#pragma unroll
            for (int o = 0; o < 8; o++) wv[o] = wl[ic][tap][oc0 + o];
#pragma unroll
            for (int o = 0; o < 8; o++)
#pragma unroll
                for (int p = 0; p < 8; p++)
                    acc[o][p] = fmaf(wv[o], areg[di][dj + p], acc[o][p]);
        }
    }
    // NHWC store: for each pixel p, pack 8 consecutive oc -> 16B
#pragma unroll
    for (int p = 0; p < 8; p++) {
        unsigned wd[4];
#pragma unroll
        for (int q = 0; q < 4; q++)
            wd[q] = (unsigned)f2bu(acc[2 * q][p]) | ((unsigned)f2bu(acc[2 * q + 1][p]) << 16);
        size_t addr = ((size_t)((b * 256 + r0 + row) * 256 + c0 + chof + p)) * 64 + oc0;
        uint4 vv; vv.x = wd[0]; vv.y = wd[1]; vv.z = wd[2]; vv.w = wd[3];
        *reinterpret_cast<uint4*>(out + addr) = vv;
    }
}

// ---------------- weight packing ----------------
// WPa layout per conv: uint4 index = ((icc*9+tap)*4+ocb)*64 + lane;
// lane holds A[row=oc=(ocb*16+(l&15))][k=ic=icc*32+(l>>4)*8+j], j=0..7
__global__ void k_wprep(const float* __restrict__ wsv, u16* __restrict__ wp) {
    int bid = blockIdx.x;                  // 216 = 3 convs * 72
    int conv = bid / 72, fg = bid % 72;
    int icc = fg / 36, t2 = fg % 36, tap = t2 / 4, ocb = t2 % 4;
    int l = threadIdx.x;                   // 64
    int oc = ocb * 16 + (l & 15);
    unsigned wd[4];
#pragma unroll
    for (int q = 0; q < 4; q++) {
        int ic0 = icc * 32 + (l >> 4) * 8 + 2 * q;
        float v0 = wsv[conv * 36864 + (oc * 64 + ic0) * 9 + tap];
        float v1 = wsv[conv * 36864 + (oc * 64 + ic0 + 1) * 9 + tap];
        wd[q] = (unsigned)f2bu(v0) | ((unsigned)f2bu(v1) << 16);
    }
    uint4 vv; vv.x = wd[0]; vv.y = wd[1]; vv.z = wd[2]; vv.w = wd[3];
    reinterpret_cast<uint4*>(wp)[conv * 4608 + fg * 64 + l] = vv;
}

// conv5: GEMM channels ic' : [0,64)=enc(concat 30+ic'), [64,67)=img, [67,96)=0
__global__ void k_wprep5(const float* __restrict__ acw, u16* __restrict__ wp5) {
    int fg = blockIdx.x;                   // 108 = 3 icc * 9 tap * 4 ocb
    int icc = fg / 36, t2 = fg % 36, tap = t2 / 4, ocb = t2 % 4;
    int l = threadIdx.x;
    int oc = ocb * 16 + (l & 15);
    unsigned wd[4];
#pragma unroll
    for (int q = 0; q < 4; q++) {
        unsigned out2 = 0;
#pragma unroll
        for (int h = 0; h < 2; h++) {
            int icp = icc * 32 + (l >> 4) * 8 + 2 * q + h;
            float v = 0.f;
            if (icp < 67) v = acw[(oc * 97 + 30 + icp) * 9 + tap];
            out2 |= ((unsigned)f2bu(v)) << (16 * h);
        }
        wd[q] = out2;
    }
    uint4 vv; vv.x = wd[0]; vv.y = wd[1]; vv.z = wd[2]; vv.w = wd[3];
    reinterpret_cast<uint4*>(wp5)[fg * 64 + l] = vv;
}

// WS[oc][ic<30][class] = sum of conv5 weights over taps valid for border class
__global__ void k_wsum(const float* __restrict__ acw, float* __restrict__ wsum) {
    for (int e = threadIdx.x; e < 17280; e += 256) {
        int oc = e / 270, r2 = e % 270, ic = r2 / 9, cls = r2 % 9;
        int cy = cls / 3, cx = cls % 3;
        int dil = (cy == 0) ? 1 : 0, dih = (cy == 2) ? 1 : 2;
        int djl = (cx == 0) ? 1 : 0, djh = (cx == 2) ? 1 : 2;
        float s = 0.f;
        for (int di = dil; di <= dih; di++)
            for (int dj = djl; dj <= djh; dj++)
                s += acw[(oc * 97 + ic) * 9 + di * 3 + dj];
        wsum[e] = s;
    }
}

// M[b][oc][cls] = sum_ic msg * WS
__global__ void k_msgM(const float* __restrict__ msg, const float* __restrict__ wsum,
                       float* __restrict__ M) {
    int b = blockIdx.x;
    for (int t = threadIdx.x; t < 576; t += 256) {
        int oc = t / 9, cls = t % 9;
        float s = 0.f;
        for (int ic = 0; ic < 30; ic++)
            s += msg[b * 30 + ic] * wsum[oc * 270 + ic * 9 + cls];
        M[b * 576 + t] = s;
    }
}

// ---------------- MFMA conv3x3 (convs 2-5) ----------------
// MODE 0: CIN=64 (src = prev raw bf16 NHWC, BN+relu fused)
// MODE 1: conv5 (chunks 0,1 = enc from y4 +wm-corr on c0; chunk 2 = image; +M)
template <int MODE>
__global__ __launch_bounds__(256, 2) void k_cmfma(
    const u16* __restrict__ src, const u16* __restrict__ wp,
    const float* __restrict__ st, const float* __restrict__ img,
    const float* __restrict__ dlt, const float* __restrict__ tw,
    const float* __restrict__ Mterm, u16* __restrict__ out) {
    const int NC = (MODE == 0) ? 2 : 3;
    __shared__ __align__(16) u16 ain[4 * 324 * 8];   // [kb][ly*18+lx][j]
    __shared__ float sst[128];
    __shared__ float twl[512];
    __shared__ float dl[60];
    __shared__ float Ml[576];

    int tid = threadIdx.x;
    int wv = tid >> 6, l = tid & 63;
    int b = blockIdx.z, y0 = blockIdx.y * 16, x0 = blockIdx.x * 16;

    if (tid < 128) sst[tid] = st[tid];
    if (MODE == 1) {
        twl[tid] = tw[tid]; twl[tid + 256] = tw[tid + 256];
        if (tid < 60) dl[tid] = dlt[b * 60 + tid];
        for (int i = tid; i < 576; i += 256) Ml[i] = Mterm[b * 576 + i];
    }

    f32x4 acc[4][4];
#pragma unroll
    for (int nt = 0; nt < 4; nt++)
#pragma unroll
        for (int ob = 0; ob < 4; ob++) acc[nt][ob] = (f32x4)(0.f);

    const uint4* wq = reinterpret_cast<const uint4*>(wp);
    const uint4* ap = reinterpret_cast<const uint4*>(ain);
    const int bl = (l >> 4) * 324 + (l & 15);
    const int wv4 = wv * 4;

#pragma unroll 1
    for (int icc = 0; icc < NC; icc++) {
        __syncthreads();
        if (MODE == 1 && icc == 2) {
            // image channels (fp32 CHW) into j=0..2 of kb=0; rest zero
            for (int i = tid; i < 1296; i += 256) {
                int kb = i / 324, r = i - kb * 324;
                int ly = r / 18, lx = r - ly * 18;
                int gy = y0 - 1 + ly, gx = x0 - 1 + lx;
                uint4 pk; pk.x = 0; pk.y = 0; pk.z = 0; pk.w = 0;
                if (kb == 0 && (unsigned)gy < 256u && (unsigned)gx < 256u) {
                    float v0 = img[(b * 3 + 0) * NPX + gy * 256 + gx];
                    float v1 = img[(b * 3 + 1) * NPX + gy * 256 + gx];
                    float v2 = img[(b * 3 + 2) * NPX + gy * 256 + gx];
                    pk.x = (unsigned)f2bu(v0) | ((unsigned)f2bu(v1) << 16);
                    pk.y = (unsigned)f2bu(v2);
                }
                reinterpret_cast<uint4*>(ain)[i] = pk;
            }
        } else {
            for (int i = tid; i < 1296; i += 256) {
                int kb = i / 324, r = i - kb * 324;
                int ly = r / 18, lx = r - ly * 18;
                int gy = y0 - 1 + ly, gx = x0 - 1 + lx;
                uint4 pk; pk.x = 0; pk.y = 0; pk.z = 0; pk.w = 0;
                if ((unsigned)gy < 256u && (unsigned)gx < 256u) {
                    size_t gaddr = ((size_t)((b * 256 + gy) * 256 + gx)) * 64 + icc * 32 + kb * 8;
                    uint4 u = *reinterpret_cast<const uint4*>(src + gaddr);
                    unsigned wd[4] = {u.x, u.y, u.z, u.w};
                    float f[8];
                    int cb = icc * 32 + kb * 8;
#pragma unroll
                    for (int q = 0; q < 4; q++) {
                        f[2 * q]     = fmaxf(bfu2f(wd[q] & 0xffffu) * sst[2 * (cb + 2 * q)] + sst[2 * (cb + 2 * q) + 1], 0.f);
                        f[2 * q + 1] = fmaxf(bfu2f(wd[q] >> 16)     * sst[2 * (cb + 2 * q + 1)] + sst[2 * (cb + 2 * q + 1) + 1], 0.f);
                    }
                    if (MODE == 1 && icc == 0 && kb == 0) {
                        float corr = 0.f;
#pragma unroll
                        for (int p = 0; p < 30; p++) {
                            int t = (WM_R_[p] * gy + WM_C_[p] * gx) & 255;
                            corr += dl[2 * p] * twl[t] + dl[2 * p + 1] * twl[256 + t];
                        }
                        f[0] += corr * (1.0f / 65536.0f);
                    }
                    unsigned po[4];
#pragma unroll
                    for (int q = 0; q < 4; q++)
                        po[q] = (unsigned)f2bu(f[2 * q]) | ((unsigned)f2bu(f[2 * q + 1]) << 16);
                    pk.x = po[0]; pk.y = po[1]; pk.z = po[2]; pk.w = po[3];
                }
                reinterpret_cast<uint4*>(ain)[i] = pk;
            }
        }
        __syncthreads();

        uint4 a0, a1, a2, a3, n0, n1, n2, n3;
        {
            const uint4* q = wq + ((icc * 9 + 0) * 256 + l);
            a0 = q[0]; a1 = q[64]; a2 = q[128]; a3 = q[192];
        }
#pragma unroll
        for (int tap = 0; tap < 9; tap++) {
            if (tap < 8) {
                const uint4* q = wq + ((icc * 9 + tap + 1) * 256 + l);
                n0 = q[0]; n1 = q[64]; n2 = q[128]; n3 = q[192];
            }
            const int di = tap / 3, dj = tap % 3;
#pragma unroll
            for (int nt = 0; nt < 4; nt++) {
                uint4 braw = ap[bl + (wv4 + nt + di) * 18 + dj];
                bfrag_t bf = __builtin_bit_cast(bfrag_t, braw);
                acc[nt][0] = __builtin_amdgcn_mfma_f32_16x16x32_bf16(
                    __builtin_bit_cast(bfrag_t, a0), bf, acc[nt][0], 0, 0, 0);
                acc[nt][1] = __builtin_amdgcn_mfma_f32_16x16x32_bf16(
                    __builtin_bit_cast(bfrag_t, a1), bf, acc[nt][1], 0, 0, 0);
                acc[nt][2] = __builtin_amdgcn_mfma_f32_16x16x32_bf16(
                    __builtin_bit_cast(bfrag_t, a2), bf, acc[nt][2], 0, 0, 0);
                acc[nt][3] = __builtin_amdgcn_mfma_f32_16x16x32_bf16(
                    __builtin_bit_cast(bfrag_t, a3), bf, acc[nt][3], 0, 0, 0);
            }
            a0 = n0; a1 = n1; a2 = n2; a3 = n3;
        }
    }

    // epilogue: (+M term for MODE1), pack 4 oc -> 8B, NHWC store
    int x = x0 + (l & 15);
    int ocq = (l >> 4) * 4;
    int clsx = (x == 0) ? 0 : ((x == 255) ? 2 : 1);
#pragma unroll
    for (int nt = 0; nt < 4; nt++) {
        int y = y0 + wv4 + nt;
#pragma unroll
        for (int ob = 0; ob < 4; ob++) {
            int oc = ob * 16 + ocq;
            float v0 = acc[nt][ob][0], v1 = acc[nt][ob][1];
            float v2 = acc[nt][ob][2], v3 = acc[nt][ob][3];
            if (MODE == 1) {
                int cls = ((y == 0) ? 0 : ((y == 255) ? 6 : 3)) + clsx;
                v0 += Ml[(oc + 0) * 9 + cls];
                v1 += Ml[(oc + 1) * 9 + cls];
                v2 += Ml[(oc + 2) * 9 + cls];
                v3 += Ml[(oc + 3) * 9 + cls];
            }
            uint2 pk;
            pk.x = (unsigned)f2bu(v0) | ((unsigned)f2bu(v1) << 16);
            pk.y = (unsigned)f2bu(v2) | ((unsigned)f2bu(v3) << 16);
            size_t addr = ((size_t)((b * 256 + y) * 256 + x)) * 64 + oc;
            *reinterpret_cast<uint2*>(out + addr) = pk;
        }
    }
}

// ---------------- BN stats over NHWC raw bf16 ----------------
__global__ void k_stats(const u16* __restrict__ y, float* __restrict__ part) {
    __shared__ float red[2048];
    int blk = blockIdx.x, tid = threadIdx.x;
    int j = tid & 7, g = tid >> 3;
    float s1[8], s2[8];
#pragma unroll
    for (int k = 0; k < 8; k++) { s1[k] = 0.f; s2[k] = 0.f; }
    for (int it = 0; it < 64; it++) {
        int px = blk * 2048 + it * 32 + g;
        uint4 u = *reinterpret_cast<const uint4*>(y + (size_t)px * 64 + j * 8);
        unsigned wd[4] = {u.x, u.y, u.z, u.w};
#pragma unroll
        for (int q = 0; q < 4; q++) {
            float v0 = bfu2f(wd[q] & 0xffffu), v1 = bfu2f(wd[q] >> 16);
            s1[2 * q] += v0; s2[2 * q] += v0 * v0;
            s1[2 * q + 1] += v1; s2[2 * q + 1] += v1 * v1;
        }
    }
#pragma unroll
    for (int k = 0; k < 8; k++) red[tid * 8 + k] = s1[k];
    __syncthreads();
    if (tid < 64) {
        float a = 0.f;
        for (int gg = 0; gg < 32; gg++) a += red[gg * 64 + tid];
        part[blk * 128 + tid * 2] = a;
    }
    __syncthreads();
#pragma unroll
    for (int k = 0; k < 8; k++) red[tid * 8 + k] = s2[k];
    __syncthreads();
    if (tid < 64) {
        float a = 0.f;
        for (int gg = 0; gg < 32; gg++) a += red[gg * 64 + tid];
        part[blk * 128 + tid * 2 + 1] = a;
    }
}

__global__ void k_finalize(const float* __restrict__ part, const float* __restrict__ g,
                           const float* __restrict__ be, float* __restrict__ st) {
    __shared__ double d1[256], d2[256];
    int tid = threadIdx.x;
    int c = tid >> 2, q = tid & 3;
    double S1 = 0.0, S2 = 0.0;
    for (int k = 0; k < 64; k++) {
        int blk = q * 64 + k;
        S1 += (double)part[blk * 128 + c * 2];
        S2 += (double)part[blk * 128 + c * 2 + 1];
    }
    d1[tid] = S1; d2[tid] = S2;
    __syncthreads();
    if (tid < 64) {
        double T1 = 0.0, T2 = 0.0;
        for (int qq = 0; qq < 4; qq++) { T1 += d1[tid * 4 + qq]; T2 += d2[tid * 4 + qq]; }
        const double Nn = 524288.0;
        double mean = T1 / Nn;
        double var = T2 / Nn - mean * mean;
        float s = (float)((double)g[tid] / sqrt(var + 1e-5));
        float t = (float)((double)be[tid] - mean * (double)s);
        st[tid * 2] = s; st[tid * 2 + 1] = t;
    }
}

// ---------------- watermark coefficient passes ----------------
// row-DFT of relu(bn(y4)) ch0 over 6 wm rows. G[b][r][x][2]
__global__ void k_wmG(const u16* __restrict__ y4, const float* __restrict__ st,
                      const float* __restrict__ tw, float* __restrict__ G) {
    __shared__ float twl[512];
    int b = blockIdx.x, x = threadIdx.x;
    twl[x] = tw[x]; twl[x + 256] = tw[x + 256];
    __syncthreads();
    float s0 = st[0], t0 = st[1];
    float gr[6], gi[6];
#pragma unroll
    for (int r = 0; r < 6; r++) { gr[r] = 0.f; gi[r] = 0.f; }
    for (int y = 0; y < 256; y++) {
        float v = fmaxf(bfu2f((unsigned)y4[((size_t)((b * 256 + y) * 256 + x)) * 64]) * s0 + t0, 0.f);
#pragma unroll
        for (int r = 0; r < 6; r++) {
            int t = ((124 + r) * y) & 255;
            gr[r] += v * twl[t];
            gi[r] += v * twl[256 + t];
        }
    }
#pragma unroll
    for (int r = 0; r < 6; r++) {
        G[((b * 6 + r) * 256 + x) * 2]     = gr[r];
        G[((b * 6 + r) * 256 + x) * 2 + 1] = gi[r];
    }
}

// column pass: F[p] then dlt = m - F
__global__ void k_wmC(const float* __restrict__ G, const float* __restrict__ msg,
                      const float* __restrict__ tw, float* __restrict__ dlt) {
    __shared__ float twl[512];
    __shared__ float fr[256], fi[256];
    int b = blockIdx.x, tid = threadIdx.x;
    twl[tid] = tw[tid]; twl[tid + 256] = tw[tid + 256];
    __syncthreads();
    int p = tid >> 3, part = tid & 7;
    float Fr = 0.f, Fi = 0.f;
    if (p < 30) {
        int rp = WM_R_[p] - 124, c = WM_C_[p];
        for (int xx = part * 32; xx < part * 32 + 32; xx++) {
            float gr = G[((b * 6 + rp) * 256 + xx) * 2];
            float gi = G[((b * 6 + rp) * 256 + xx) * 2 + 1];
            int u = (c * xx) & 255;
            Fr += gr * twl[u] - gi * twl[256 + u];
            Fi += gr * twl[256 + u] + gi * twl[u];
        }
    }
    fr[tid] = Fr; fi[tid] = Fi;
    __syncthreads();
    if (p < 30 && part == 0) {
        float sr = 0.f, si = 0.f;
        for (int k = 0; k < 8; k++) { sr += fr[p * 8 + k]; si += fi[p * 8 + k]; }
        float m = msg[b * 30 + p];
        dlt[b * 60 + p * 2]     = m - sr;
        dlt[b * 60 + p * 2 + 1] = m - si;
    }
}

// ---------------- final 1x1 conv, NHWC in, CHW fp32 out ----------------
__global__ void k_final(const u16* __restrict__ y5, const float* __restrict__ st,
                        const float* __restrict__ fw, const float* __restrict__ fb,
                        float* __restrict__ out) {
    __shared__ float fwl[192];
    __shared__ float sl[64], tl[64];
    __shared__ float fbl[3];
    int tid = threadIdx.x;
    if (tid < 192) fwl[tid] = fw[tid];
    if (tid < 64) { sl[tid] = st[tid * 2]; tl[tid] = st[tid * 2 + 1]; }
    if (tid < 3) fbl[tid] = fb[tid];
    __syncthreads();
    int e = blockIdx.x * 256 + tid;
    int b = e >> 16, px = e & 65535;
    float a0 = fbl[0], a1 = fbl[1], a2 = fbl[2];
    const u16* rowp = y5 + (size_t)e * 64;
    for (int cb = 0; cb < 8; cb++) {
        uint4 u = *reinterpret_cast<const uint4*>(rowp + cb * 8);
        unsigned wd[4] = {u.x, u.y, u.z, u.w};
#pragma unroll
        for (int q = 0; q < 4; q++) {
            int c = cb * 8 + 2 * q;
            float v0 = fmaxf(bfu2f(wd[q] & 0xffffu) * sl[c] + tl[c], 0.f);
            float v1 = fmaxf(bfu2f(wd[q] >> 16) * sl[c + 1] + tl[c + 1], 0.f);
            a0 += v0 * fwl[c] + v1 * fwl[c + 1];
            a1 += v0 * fwl[64 + c] + v1 * fwl[64 + c + 1];
            a2 += v0 * fwl[128 + c] + v1 * fwl[128 + c + 1];
        }
    }
    out[(b * 3 + 0) * NPX + px] = a0;
    out[(b * 3 + 1) * NPX + px] = a1;
    out[(b * 3 + 2) * NPX + px] = a2;
}

extern "C" void kernel_launch(void* const* d_in, const int* in_sizes, int n_in,
                              void* d_out, int out_size, void* d_ws, size_t ws_size,
                              hipStream_t stream) {
    (void)in_sizes; (void)n_in; (void)out_size; (void)ws_size;
    const float* image   = (const float*)d_in[0];
    const float* message = (const float*)d_in[1];
    const float* w0      = (const float*)d_in[2];
    const float* g0      = (const float*)d_in[4];
    const float* be0     = (const float*)d_in[5];
    const float* wsv     = (const float*)d_in[6];
    const float* gs      = (const float*)d_in[8];
    const float* bes     = (const float*)d_in[9];
    const float* acw     = (const float*)d_in[10];
    const float* acg     = (const float*)d_in[12];
    const float* acbe    = (const float*)d_in[13];
    const float* fw      = (const float*)d_in[14];
    const float* fb      = (const float*)d_in[15];
    float* out = (float*)d_out;

    // workspace layout — total 134,974,336 B (~128.7 MiB)
    u16* XA   = (u16*)d_ws;                // 33,554,432 u16 (64 MiB)
    u16* XB   = XA + 33554432;             // 33,554,432 u16 (64 MiB)
    // low-pass scratch ALIASES XB: XB is first written by conv2, which runs
    // after conv1 has fully consumed LP. Yb+Wb+LP = 16.2 MB < 64 MiB.
    float* Yb = (float*)XB;                // 1,241,088 f
    float* Wb = Yb + 1241088;              // 1,241,088 f
    float* LP = Wb + 1241088;              // 1,572,864 f
    u16* WPa  = XB + 33554432;             // 110,592 u16
    u16* WP5  = WPa + 110592;              // 55,296 u16
    float* TW   = (float*)(WP5 + 55296);   // 512 f
    float* D2T  = TW + 512;                // 25,856 f
    float* PART = D2T + 25856;             // 32,768 f
    float* ST   = PART + 32768;            // 128 f
    float* DLT  = ST + 128;                // 480 f
    float* G    = DLT + 480;               // 24,576 f
    float* WSm  = G + 24576;               // 17,280 f
    float* Mt   = WSm + 17280;             // 4,608 f

    dim3 cgrid(16, 16, 8);

    k_tables<<<103, 256, 0, stream>>>(TW, D2T);
    k_wprep<<<216, 64, 0, stream>>>(wsv, WPa);
    k_wprep5<<<108, 64, 0, stream>>>(acw, WP5);
    k_wsum<<<1, 256, 0, stream>>>(acw, WSm);
    k_msgM<<<8, 256, 0, stream>>>(message, WSm, Mt);

    k_lp1<<<dim3(256, 24), 128, 0, stream>>>(image, TW, Yb);
    k_lp2<<<dim3(256, 24), 128, 0, stream>>>(Yb, D2T, Wb);
    k_lp3<<<dim3(256, 24), 256, 0, stream>>>(Wb, TW, LP);

    // conv1 -> XA (raw NHWC bf16)
    k_conv1<<<cgrid, 256, 0, stream>>>(LP, w0, XA);
    k_stats<<<256, 256, 0, stream>>>(XA, PART);
    k_finalize<<<1, 256, 0, stream>>>(PART, g0, be0, ST);
    // conv2: XA -> XB (overwrites dead LP scratch)
    k_cmfma<0><<<cgrid, 256, 0, stream>>>(XA, WPa + 0 * 36864, ST, nullptr, nullptr, nullptr, nullptr, XB);
    k_stats<<<256, 256, 0, stream>>>(XB, PART);
    k_finalize<<<1, 256, 0, stream>>>(PART, gs + 0, bes + 0, ST);
    // conv3: XB -> XA
    k_cmfma<0><<<cgrid, 256, 0, stream>>>(XB, WPa + 1 * 36864, ST, nullptr, nullptr, nullptr, nullptr, XA);
    k_stats<<<256, 256, 0, stream>>>(XA, PART);
    k_finalize<<<1, 256, 0, stream>>>(PART, gs + 64, bes + 64, ST);
    // conv4: XA -> XB (raw y4)
    k_cmfma<0><<<cgrid, 256, 0, stream>>>(XA, WPa + 2 * 36864, ST, nullptr, nullptr, nullptr, nullptr, XB);
    k_stats<<<256, 256, 0, stream>>>(XB, PART);
    k_finalize<<<1, 256, 0, stream>>>(PART, gs + 128, bes + 128, ST);
    // watermark deltas from y4 ch0
    k_wmG<<<8, 256, 0, stream>>>(XB, ST, TW, G);
    k_wmC<<<8, 256, 0, stream>>>(G, message, TW, DLT);
    // conv5 (enc staged from y4 + corr; img; msg via M term) -> XA
    k_cmfma<1><<<cgrid, 256, 0, stream>>>(XB, WP5, ST, image, DLT, TW, Mt, XA);
    k_stats<<<256, 256, 0, stream>>>(XA, PART);
    k_finalize<<<1, 256, 0, stream>>>(PART, acg, acbe, ST);
    // final 1x1 conv
    k_final<<<2048, 256, 0, stream>>>(XA, ST, fw, fb, out);
}

// Round 5
// 884.621 us; speedup vs baseline: 3.4139x; 1.0412x over previous
//
#include <hip/hip_runtime.h>
#include <math.h>

// ---------------------------------------------------------------------------
// Encoder_75557064671564 — MFMA bf16 conv stack, NHWC intermediates.
//
// ROUND-5: lp chain + wmG restructured for ILP/occupancy (was latency-bound:
// k_lp2 132 us with VALUBusy 25%). fp64 math kept; 8 accumulator chains per
// thread; LDS-staged operands; Y re-laid-out [kxi][ch][y], d2t -> [kxi][d].
// Workspace total unchanged: 134,974,336 B (~128.7 MiB); LP scratch aliases XB.
// ---------------------------------------------------------------------------

#define NPX 65536
typedef unsigned short u16;
typedef __bf16 bfrag_t __attribute__((ext_vector_type(8)));
typedef float f32x4 __attribute__((ext_vector_type(4)));

__constant__ int WM_R_[30] = {124, 125,125,125,125,125, 126,126,126,126,126,126,126,
                              127,127,127,127,127,127,127,
                              128,128,128,128,128,128,128,128,128, 129};
__constant__ int WM_C_[30] = {128, 126,127,128,129,130, 125,126,127,128,129,130,131,
                              125,126,127,128,129,130,131,
                              124,125,126,127,128,129,130,131,132, 125};

__device__ __forceinline__ float bfu2f(unsigned int bits) {
    return __uint_as_float(bits << 16);
}
__device__ __forceinline__ u16 f2bu(float f) {
    unsigned int u = __float_as_uint(f);
    u += 0x7fffu + ((u >> 16) & 1u);
    return (u16)(u >> 16);
}

// ---------------- tables ----------------
// tw[0..255]=cos(-2pi t/256), tw[256..511]=sin(-2pi t/256)
// d2t[kxi][d] : Dirichlet kernel (incl 1/256) for column kxi, lag d
__global__ void k_tables(float* __restrict__ tw, float* __restrict__ d2t) {
    int idx = blockIdx.x * 256 + threadIdx.x;
    if (idx < 256) {
        double ang = -2.0 * M_PI * (double)idx / 256.0;
        tw[idx]       = (float)cos(ang);
        tw[256 + idx] = (float)sin(ang);
    }
    int q = idx - 256;
    if (q >= 0 && q < 256 * 101) {
        int d = q / 101, kxi = q - d * 101;
        int vx = (kxi <= 50) ? kxi : kxi - 101;
        int r2 = 2500 - vx * vx;
        int L = 0;
        while ((L + 1) * (L + 1) <= r2) L++;
        double s = 1.0;
        for (int v = 1; v <= L; v++) s += 2.0 * cos(2.0 * M_PI * (double)(v * d) / 256.0);
        d2t[kxi * 256 + d] = (float)(s / 256.0);
    }
}

// ---------------- low-pass chain (fp64, ILP-restructured) ----------------
// row forward DFT, keep 101 cols. Y[kxi][ch][y][2] fp32.
// grid (128, 24): block = 2 rows of one plane; 256 thr: ys=tid>>7, kxi=tid&127
__global__ __launch_bounds__(256) void k_lp1(const float* __restrict__ img,
        const float* __restrict__ tw, float* __restrict__ Y) {
    __shared__ double rowd[2][256];
    __shared__ double twd[512];
    int y2 = blockIdx.x, ch = blockIdx.y, tid = threadIdx.x;
    rowd[0][tid] = (double)img[ch * NPX + (2 * y2) * 256 + tid];
    rowd[1][tid] = (double)img[ch * NPX + (2 * y2 + 1) * 256 + tid];
    twd[tid]       = (double)tw[tid];
    twd[tid + 256] = (double)tw[tid + 256];
    __syncthreads();
    int ys = tid >> 7, kxi = tid & 127;
    if (kxi >= 101) return;
    int kx = (kxi <= 50) ? kxi : kxi + 155;
    int k1 = kx & 255, k2 = (2 * kx) & 255, k3 = (3 * kx) & 255, k4 = (4 * kx) & 255;
    double ar[4] = {0, 0, 0, 0}, ai[4] = {0, 0, 0, 0};
    int base = 0;
    const double* rw = rowd[ys];
    for (int x4 = 0; x4 < 256; x4 += 4) {
        int t0 = base;
        int t1 = (base + k1) & 255;
        int t2 = (base + k2) & 255;
        int t3 = (base + k3) & 255;
        double v0 = rw[x4], v1 = rw[x4 + 1], v2 = rw[x4 + 2], v3 = rw[x4 + 3];
        ar[0] += v0 * twd[t0]; ai[0] += v0 * twd[256 + t0];
        ar[1] += v1 * twd[t1]; ai[1] += v1 * twd[256 + t1];
        ar[2] += v2 * twd[t2]; ai[2] += v2 * twd[256 + t2];
        ar[3] += v3 * twd[t3]; ai[3] += v3 * twd[256 + t3];
        base = (base + k4) & 255;
    }
    double arf = (ar[0] + ar[1]) + (ar[2] + ar[3]);
    double aif = (ai[0] + ai[1]) + (ai[2] + ai[3]);
    int y = 2 * y2 + ys;
    int o = ((kxi * 24 + ch) * 256 + y) * 2;
    Y[o] = (float)arf; Y[o + 1] = (float)aif;
}

// per-column circulant. grid (101, 6): block = (kxi, 4-ch group); 256 thr:
// cs=tid>>6 (wave-uniform), y4=tid&63; outputs y in {y4+64k}. W[ch][y][kxi][2]
__global__ __launch_bounds__(256) void k_lp2(const float* __restrict__ Y,
        const float* __restrict__ d2t, float* __restrict__ W) {
    __shared__ double Ys[4][256][2];   // 16 KB
    __shared__ double Dc[256];         // 2 KB
    int kxi = blockIdx.x, chg = blockIdx.y, tid = threadIdx.x;
    const float* src = Y + (size_t)(kxi * 24 + chg * 4) * 512;
    double* ysf = (double*)Ys;
    for (int i = tid; i < 2048; i += 256) ysf[i] = (double)src[i];
    Dc[tid] = (double)d2t[kxi * 256 + tid];
    __syncthreads();
    int cs = tid >> 6, y4 = tid & 63;
    double wr[4] = {0, 0, 0, 0}, wi[4] = {0, 0, 0, 0};
    for (int yp = 0; yp < 256; yp++) {
        double yr = Ys[cs][yp][0], yi = Ys[cs][yp][1];
        double D0 = Dc[(y4 - yp) & 255];
        double D1 = Dc[(y4 + 64 - yp) & 255];
        double D2 = Dc[(y4 + 128 - yp) & 255];
        double D3 = Dc[(y4 + 192 - yp) & 255];
        wr[0] += D0 * yr; wi[0] += D0 * yi;
        wr[1] += D1 * yr; wi[1] += D1 * yi;
        wr[2] += D2 * yr; wi[2] += D2 * yi;
        wr[3] += D3 * yr; wi[3] += D3 * yi;
    }
    int ch = chg * 4 + cs;
#pragma unroll
    for (int k = 0; k < 4; k++) {
        int y = y4 + 64 * k;
        int o = ((ch * 256 + y) * 101 + kxi) * 2;
        W[o] = (float)wr[k]; W[o + 1] = (float)wi[k];
    }
}

// row inverse DFT + clip/floor/255. grid (256,24), 256 thr (one x each).
__global__ __launch_bounds__(256) void k_lp3(const float* __restrict__ W,
        const float* __restrict__ tw, float* __restrict__ lp) {
    __shared__ double wr[104], wi[104];
    __shared__ double twd[512];
    int y = blockIdx.x, ch = blockIdx.y, x = threadIdx.x;
    if (x < 101) {
        wr[x] = (double)W[((ch * 256 + y) * 101 + x) * 2];
        wi[x] = (double)W[((ch * 256 + y) * 101 + x) * 2 + 1];
    } else if (x < 104) {
        wr[x] = 0.0; wi[x] = 0.0;
    }
    twd[x] = (double)tw[x]; twd[x + 256] = (double)tw[x + 256];
    __syncthreads();
    double a[4] = {0, 0, 0, 0};
    for (int kb = 0; kb < 104; kb += 4) {
#pragma unroll
        for (int j = 0; j < 4; j++) {
            int kxi = kb + j;
            int kx = (kxi <= 50) ? kxi : kxi + 155;
            int t = (kx * x) & 255;
            a[j] += wr[kxi] * twd[t] + wi[kxi] * twd[256 + t];
        }
    }
    double acc = ((a[0] + a[1]) + (a[2] + a[3])) * (1.0 / 256.0);
    acc = floor(fmin(fmax(acc, 0.0), 255.0)) / 255.0;
    lp[ch * NPX + y * 256 + x] = (float)acc;
}

// ---------------- conv1: CIN=3, fp32 VALU, NHWC bf16 out ----------------
__global__ __launch_bounds__(256, 2) void k_conv1(
    const float* __restrict__ lp, const float* __restrict__ w0,
    u16* __restrict__ out) {
    __shared__ float wl[3][9][64];
    __shared__ float al[3][18][18];
    int tid = threadIdx.x;
    int b = blockIdx.z, r0 = blockIdx.y * 16, c0 = blockIdx.x * 16;
    int ocg = tid >> 5, pxg = tid & 31;
    int row = pxg >> 1, chof = (pxg & 1) * 8;
    int oc0 = ocg * 8;
    float acc[8][8];
#pragma unroll
    for (int o = 0; o < 8; o++)
#pragma unroll
        for (int p = 0; p < 8; p++) acc[o][p] = 0.f;
    for (int idx = tid; idx < 1728; idx += 256) {
        int ic = idx / 576, rem = idx - ic * 576;
        int tap = rem >> 6, oc = rem & 63;
        wl[ic][tap][oc] = w0[(oc * 3 + ic) * 9 + tap];
    }
    for (int idx = tid; idx < 972; idx += 256) {
        int ic = idx / 324, rem = idx - ic * 324;
        int ly = rem / 18, lx = rem - ly * 18;
        int gy = r0 - 1 + ly, gx = c0 - 1 + lx;
        float v = 0.f;
        if ((unsigned)gy < 256u && (unsigned)gx < 256u)
            v = lp[(b * 3 + ic) * NPX + gy * 256 + gx];
        al[ic][ly][lx] = v;
    }
    __syncthreads();
    for (int ic = 0; ic < 3; ic++) {
        float areg[3][10];
#pragma unroll
        for (int di = 0; di < 3; di++)
#pragma unroll
            for (int xx = 0; xx < 10; xx++) areg[di][xx] = al[ic][row + di][chof + xx];
#pragma unroll
        for (int tap = 0; tap < 9; tap++) {
            const int di = tap / 3, dj = tap % 3;
            float wv[8];
#pragma unroll
            for (int o = 0; o < 8; o++) wv[o] = wl[ic][tap][oc0 + o];
#pragma unroll
            for (int o = 0; o < 8; o++)
#pragma unroll
                for (int p = 0; p < 8; p++)
                    acc[o][p] = fmaf(wv[o], areg[di][dj + p], acc[o][p]);
        }
    }
#pragma unroll
    for (int p = 0; p < 8; p++) {
        unsigned wd[4];
#pragma unroll
        for (int q = 0; q < 4; q++)
            wd[q] = (unsigned)f2bu(acc[2 * q][p]) | ((unsigned)f2bu(acc[2 * q + 1][p]) << 16);
        size_t addr = ((size_t)((b * 256 + r0 + row) * 256 + c0 + chof + p)) * 64 + oc0;
        uint4 vv; vv.x = wd[0]; vv.y = wd[1]; vv.z = wd[2]; vv.w = wd[3];
        *reinterpret_cast<uint4*>(out + addr) = vv;
    }
}

// ---------------- weight packing ----------------
__global__ void k_wprep(const float* __restrict__ wsv, u16* __restrict__ wp) {
    int bid = blockIdx.x;                  // 216 = 3 convs * 72
    int conv = bid / 72, fg = bid % 72;
    int icc = fg / 36, t2 = fg % 36, tap = t2 / 4, ocb = t2 % 4;
    int l = threadIdx.x;                   // 64
    int oc = ocb * 16 + (l & 15);
    unsigned wd[4];
#pragma unroll
    for (int q = 0; q < 4; q++) {
        int ic0 = icc * 32 + (l >> 4) * 8 + 2 * q;
        float v0 = wsv[conv * 36864 + (oc * 64 + ic0) * 9 + tap];
        float v1 = wsv[conv * 36864 + (oc * 64 + ic0 + 1) * 9 + tap];
        wd[q] = (unsigned)f2bu(v0) | ((unsigned)f2bu(v1) << 16);
    }
    uint4 vv; vv.x = wd[0]; vv.y = wd[1]; vv.z = wd[2]; vv.w = wd[3];
    reinterpret_cast<uint4*>(wp)[conv * 4608 + fg * 64 + l] = vv;
}

__global__ void k_wprep5(const float* __restrict__ acw, u16* __restrict__ wp5) {
    int fg = blockIdx.x;                   // 108
    int icc = fg / 36, t2 = fg % 36, tap = t2 / 4, ocb = t2 % 4;
    int l = threadIdx.x;
    int oc = ocb * 16 + (l & 15);
    unsigned wd[4];
#pragma unroll
    for (int q = 0; q < 4; q++) {
        unsigned out2 = 0;
#pragma unroll
        for (int h = 0; h < 2; h++) {
            int icp = icc * 32 + (l >> 4) * 8 + 2 * q + h;
            float v = 0.f;
            if (icp < 67) v = acw[(oc * 97 + 30 + icp) * 9 + tap];
            out2 |= ((unsigned)f2bu(v)) << (16 * h);
        }
        wd[q] = out2;
    }
    uint4 vv; vv.x = wd[0]; vv.y = wd[1]; vv.z = wd[2]; vv.w = wd[3];
    reinterpret_cast<uint4*>(wp5)[fg * 64 + l] = vv;
}

__global__ void k_wsum(const float* __restrict__ acw, float* __restrict__ wsum) {
    for (int e = threadIdx.x; e < 17280; e += 256) {
        int oc = e / 270, r2 = e % 270, ic = r2 / 9, cls = r2 % 9;
        int cy = cls / 3, cx = cls % 3;
        int dil = (cy == 0) ? 1 : 0, dih = (cy == 2) ? 1 : 2;
        int djl = (cx == 0) ? 1 : 0, djh = (cx == 2) ? 1 : 2;
        float s = 0.f;
        for (int di = dil; di <= dih; di++)
            for (int dj = djl; dj <= djh; dj++)
                s += acw[(oc * 97 + ic) * 9 + di * 3 + dj];
        wsum[e] = s;
    }
}

__global__ void k_msgM(const float* __restrict__ msg, const float* __restrict__ wsum,
                       float* __restrict__ M) {
    int b = blockIdx.x;
    for (int t = threadIdx.x; t < 576; t += 256) {
        int oc = t / 9, cls = t % 9;
        float s = 0.f;
        for (int ic = 0; ic < 30; ic++)
            s += msg[b * 30 + ic] * wsum[oc * 270 + ic * 9 + cls];
        M[b * 576 + t] = s;
    }
}

// ---------------- MFMA conv3x3 (convs 2-5) ----------------
template <int MODE>
__global__ __launch_bounds__(256, 2) void k_cmfma(
    const u16* __restrict__ src, const u16* __restrict__ wp,
    const float* __restrict__ st, const float* __restrict__ img,
    const float* __restrict__ dlt, const float* __restrict__ tw,
    const float* __restrict__ Mterm, u16* __restrict__ out) {
    const int NC = (MODE == 0) ? 2 : 3;
    __shared__ __align__(16) u16 ain[4 * 324 * 8];   // [kb][ly*18+lx][j]
    __shared__ float sst[128];
    __shared__ float twl[512];
    __shared__ float dl[60];
    __shared__ float Ml[576];

    int tid = threadIdx.x;
    int wv = tid >> 6, l = tid & 63;
    int b = blockIdx.z, y0 = blockIdx.y * 16, x0 = blockIdx.x * 16;

    if (tid < 128) sst[tid] = st[tid];
    if (MODE == 1) {
        twl[tid] = tw[tid]; twl[tid + 256] = tw[tid + 256];
        if (tid < 60) dl[tid] = dlt[b * 60 + tid];
        for (int i = tid; i < 576; i += 256) Ml[i] = Mterm[b * 576 + i];
    }

    f32x4 acc[4][4];
#pragma unroll
    for (int nt = 0; nt < 4; nt++)
#pragma unroll
        for (int ob = 0; ob < 4; ob++) acc[nt][ob] = (f32x4)(0.f);

    const uint4* wq = reinterpret_cast<const uint4*>(wp);
    const uint4* ap = reinterpret_cast<const uint4*>(ain);
    const int bl = (l >> 4) * 324 + (l & 15);
    const int wv4 = wv * 4;

#pragma unroll 1
    for (int icc = 0; icc < NC; icc++) {
        __syncthreads();
        if (MODE == 1 && icc == 2) {
            for (int i = tid; i < 1296; i += 256) {
                int kb = i / 324, r = i - kb * 324;
                int ly = r / 18, lx = r - ly * 18;
                int gy = y0 - 1 + ly, gx = x0 - 1 + lx;
                uint4 pk; pk.x = 0; pk.y = 0; pk.z = 0; pk.w = 0;
                if (kb == 0 && (unsigned)gy < 256u && (unsigned)gx < 256u) {
                    float v0 = img[(b * 3 + 0) * NPX + gy * 256 + gx];
                    float v1 = img[(b * 3 + 1) * NPX + gy * 256 + gx];
                    float v2 = img[(b * 3 + 2) * NPX + gy * 256 + gx];
                    pk.x = (unsigned)f2bu(v0) | ((unsigned)f2bu(v1) << 16);
                    pk.y = (unsigned)f2bu(v2);
                }
                reinterpret_cast<uint4*>(ain)[i] = pk;
            }
        } else {
            for (int i = tid; i < 1296; i += 256) {
                int kb = i / 324, r = i - kb * 324;
                int ly = r / 18, lx = r - ly * 18;
                int gy = y0 - 1 + ly, gx = x0 - 1 + lx;
                uint4 pk; pk.x = 0; pk.y = 0; pk.z = 0; pk.w = 0;
                if ((unsigned)gy < 256u && (unsigned)gx < 256u) {
                    size_t gaddr = ((size_t)((b * 256 + gy) * 256 + gx)) * 64 + icc * 32 + kb * 8;
                    uint4 u = *reinterpret_cast<const uint4*>(src + gaddr);
                    unsigned wd[4] = {u.x, u.y, u.z, u.w};
                    float f[8];
                    int cb = icc * 32 + kb * 8;
#pragma unroll
                    for (int q = 0; q < 4; q++) {
                        f[2 * q]     = fmaxf(bfu2f(wd[q] & 0xffffu) * sst[2 * (cb + 2 * q)] + sst[2 * (cb + 2 * q) + 1], 0.f);
                        f[2 * q + 1] = fmaxf(bfu2f(wd[q] >> 16)     * sst[2 * (cb + 2 * q + 1)] + sst[2 * (cb + 2 * q + 1) + 1], 0.f);
                    }
                    if (MODE == 1 && icc == 0 && kb == 0) {
                        float corr = 0.f;
#pragma unroll
                        for (int p = 0; p < 30; p++) {
                            int t = (WM_R_[p] * gy + WM_C_[p] * gx) & 255;
                            corr += dl[2 * p] * twl[t] + dl[2 * p + 1] * twl[256 + t];
                        }
                        f[0] += corr * (1.0f / 65536.0f);
                    }
                    unsigned po[4];
#pragma unroll
                    for (int q = 0; q < 4; q++)
                        po[q] = (unsigned)f2bu(f[2 * q]) | ((unsigned)f2bu(f[2 * q + 1]) << 16);
                    pk.x = po[0]; pk.y = po[1]; pk.z = po[2]; pk.w = po[3];
                }
                reinterpret_cast<uint4*>(ain)[i] = pk;
            }
        }
        __syncthreads();

        uint4 a0, a1, a2, a3, n0, n1, n2, n3;
        {
            const uint4* q = wq + ((icc * 9 + 0) * 256 + l);
            a0 = q[0]; a1 = q[64]; a2 = q[128]; a3 = q[192];
        }
#pragma unroll
        for (int tap = 0; tap < 9; tap++) {
            if (tap < 8) {
                const uint4* q = wq + ((icc * 9 + tap + 1) * 256 + l);
                n0 = q[0]; n1 = q[64]; n2 = q[128]; n3 = q[192];
            }
            const int di = tap / 3, dj = tap % 3;
#pragma unroll
            for (int nt = 0; nt < 4; nt++) {
                uint4 braw = ap[bl + (wv4 + nt + di) * 18 + dj];
                bfrag_t bf = __builtin_bit_cast(bfrag_t, braw);
                acc[nt][0] = __builtin_amdgcn_mfma_f32_16x16x32_bf16(
                    __builtin_bit_cast(bfrag_t, a0), bf, acc[nt][0], 0, 0, 0);
                acc[nt][1] = __builtin_amdgcn_mfma_f32_16x16x32_bf16(
                    __builtin_bit_cast(bfrag_t, a1), bf, acc[nt][1], 0, 0, 0);
                acc[nt][2] = __builtin_amdgcn_mfma_f32_16x16x32_bf16(
                    __builtin_bit_cast(bfrag_t, a2), bf, acc[nt][2], 0, 0, 0);
                acc[nt][3] = __builtin_amdgcn_mfma_f32_16x16x32_bf16(
                    __builtin_bit_cast(bfrag_t, a3), bf, acc[nt][3], 0, 0, 0);
            }
            a0 = n0; a1 = n1; a2 = n2; a3 = n3;
        }
    }

    int x = x0 + (l & 15);
    int ocq = (l >> 4) * 4;
    int clsx = (x == 0) ? 0 : ((x == 255) ? 2 : 1);
#pragma unroll
    for (int nt = 0; nt < 4; nt++) {
        int y = y0 + wv4 + nt;
#pragma unroll
        for (int ob = 0; ob < 4; ob++) {
            int oc = ob * 16 + ocq;
            float v0 = acc[nt][ob][0], v1 = acc[nt][ob][1];
            float v2 = acc[nt][ob][2], v3 = acc[nt][ob][3];
            if (MODE == 1) {
                int cls = ((y == 0) ? 0 : ((y == 255) ? 6 : 3)) + clsx;
                v0 += Ml[(oc + 0) * 9 + cls];
                v1 += Ml[(oc + 1) * 9 + cls];
                v2 += Ml[(oc + 2) * 9 + cls];
                v3 += Ml[(oc + 3) * 9 + cls];
            }
            uint2 pk;
            pk.x = (unsigned)f2bu(v0) | ((unsigned)f2bu(v1) << 16);
            pk.y = (unsigned)f2bu(v2) | ((unsigned)f2bu(v3) << 16);
            size_t addr = ((size_t)((b * 256 + y) * 256 + x)) * 64 + oc;
            *reinterpret_cast<uint2*>(out + addr) = pk;
        }
    }
}

// ---------------- BN stats over NHWC raw bf16 ----------------
__global__ void k_stats(const u16* __restrict__ y, float* __restrict__ part) {
    __shared__ float red[2048];
    int blk = blockIdx.x, tid = threadIdx.x;
    int j = tid & 7, g = tid >> 3;
    float s1[8], s2[8];
#pragma unroll
    for (int k = 0; k < 8; k++) { s1[k] = 0.f; s2[k] = 0.f; }
    for (int it = 0; it < 64; it++) {
        int px = blk * 2048 + it * 32 + g;
        uint4 u = *reinterpret_cast<const uint4*>(y + (size_t)px * 64 + j * 8);
        unsigned wd[4] = {u.x, u.y, u.z, u.w};
#pragma unroll
        for (int q = 0; q < 4; q++) {
            float v0 = bfu2f(wd[q] & 0xffffu), v1 = bfu2f(wd[q] >> 16);
            s1[2 * q] += v0; s2[2 * q] += v0 * v0;
            s1[2 * q + 1] += v1; s2[2 * q + 1] += v1 * v1;
        }
    }
#pragma unroll
    for (int k = 0; k < 8; k++) red[tid * 8 + k] = s1[k];
    __syncthreads();
    if (tid < 64) {
        float a = 0.f;
        for (int gg = 0; gg < 32; gg++) a += red[gg * 64 + tid];
        part[blk * 128 + tid * 2] = a;
    }
    __syncthreads();
#pragma unroll
    for (int k = 0; k < 8; k++) red[tid * 8 + k] = s2[k];
    __syncthreads();
    if (tid < 64) {
        float a = 0.f;
        for (int gg = 0; gg < 32; gg++) a += red[gg * 64 + tid];
        part[blk * 128 + tid * 2 + 1] = a;
    }
}

__global__ void k_finalize(const float* __restrict__ part, const float* __restrict__ g,
                           const float* __restrict__ be, float* __restrict__ st) {
    __shared__ double d1[256], d2[256];
    int tid = threadIdx.x;
    int c = tid >> 2, q = tid & 3;
    double S1 = 0.0, S2 = 0.0;
    for (int k = 0; k < 64; k++) {
        int blk = q * 64 + k;
        S1 += (double)part[blk * 128 + c * 2];
        S2 += (double)part[blk * 128 + c * 2 + 1];
    }
    d1[tid] = S1; d2[tid] = S2;
    __syncthreads();
    if (tid < 64) {
        double T1 = 0.0, T2 = 0.0;
        for (int qq = 0; qq < 4; qq++) { T1 += d1[tid * 4 + qq]; T2 += d2[tid * 4 + qq]; }
        const double Nn = 524288.0;
        double mean = T1 / Nn;
        double var = T2 / Nn - mean * mean;
        float s = (float)((double)g[tid] / sqrt(var + 1e-5));
        float t = (float)((double)be[tid] - mean * (double)s);
        st[tid * 2] = s; st[tid * 2 + 1] = t;
    }
}

// ---------------- watermark coefficient passes ----------------
// row-DFT of relu(bn(y4)) ch0 over 6 wm rows, parallelized.
// grid (8, 8): (b, xg); 256 thr: xs=tid&31 -> x=xg*32+xs, yg=tid>>5
__global__ void k_wmG(const u16* __restrict__ y4, const float* __restrict__ st,
                      const float* __restrict__ tw, float* __restrict__ G) {
    __shared__ float twl[512];
    __shared__ float red[256][12];
    int b = blockIdx.x, xg = blockIdx.y, tid = threadIdx.x;
    twl[tid] = tw[tid]; twl[tid + 256] = tw[tid + 256];
    __syncthreads();
    int xs = tid & 31, x = xg * 32 + xs, yg = tid >> 5;
    float s0 = st[0], t0 = st[1];
    float gr[6], gi[6];
#pragma unroll
    for (int r = 0; r < 6; r++) { gr[r] = 0.f; gi[r] = 0.f; }
    for (int yy = 0; yy < 32; yy++) {
        int y = yg * 32 + yy;
        float v = fmaxf(bfu2f((unsigned)y4[((size_t)((b * 256 + y) * 256 + x)) * 64]) * s0 + t0, 0.f);
#pragma unroll
        for (int r = 0; r < 6; r++) {
            int t = ((124 + r) * y) & 255;
            gr[r] += v * twl[t];
            gi[r] += v * twl[256 + t];
        }
    }
#pragma unroll
    for (int r = 0; r < 6; r++) { red[tid][2 * r] = gr[r]; red[tid][2 * r + 1] = gi[r]; }
    __syncthreads();
    for (int e = tid; e < 384; e += 256) {
        int xs2 = e & 31, c = e >> 5;
        float s = 0.f;
        for (int g = 0; g < 8; g++) s += red[g * 32 + xs2][c];
        int r = c >> 1, ri = c & 1;
        G[((b * 6 + r) * 256 + (xg * 32 + xs2)) * 2 + ri] = s;
    }
}

// column pass: F[p] then dlt = m - F
__global__ void k_wmC(const float* __restrict__ G, const float* __restrict__ msg,
                      const float* __restrict__ tw, float* __restrict__ dlt) {
    __shared__ float twl[512];
    __shared__ float fr[256], fi[256];
    int b = blockIdx.x, tid = threadIdx.x;
    twl[tid] = tw[tid]; twl[tid + 256] = tw[tid + 256];
    __syncthreads();
    int p = tid >> 3, part = tid & 7;
    float Fr = 0.f, Fi = 0.f;
    if (p < 30) {
        int rp = WM_R_[p] - 124, c = WM_C_[p];
        for (int xx = part * 32; xx < part * 32 + 32; xx++) {
            float gr = G[((b * 6 + rp) * 256 + xx) * 2];
            float gi = G[((b * 6 + rp) * 256 + xx) * 2 + 1];
            int u = (c * xx) & 255;
            Fr += gr * twl[u] - gi * twl[256 + u];
            Fi += gr * twl[256 + u] + gi * twl[u];
        }
    }
    fr[tid] = Fr; fi[tid] = Fi;
    __syncthreads();
    if (p < 30 && part == 0) {
        float sr = 0.f, si = 0.f;
        for (int k = 0; k < 8; k++) { sr += fr[p * 8 + k]; si += fi[p * 8 + k]; }
        float m = msg[b * 30 + p];
        dlt[b * 60 + p * 2]     = m - sr;
        dlt[b * 60 + p * 2 + 1] = m - si;
    }
}

// ---------------- final 1x1 conv, NHWC in, CHW fp32 out ----------------
__global__ void k_final(const u16* __restrict__ y5, const float* __restrict__ st,
                        const float* __restrict__ fw, const float* __restrict__ fb,
                        float* __restrict__ out) {
    __shared__ float fwl[192];
    __shared__ float sl[64], tl[64];
    __shared__ float fbl[3];
    int tid = threadIdx.x;
    if (tid < 192) fwl[tid] = fw[tid];
    if (tid < 64) { sl[tid] = st[tid * 2]; tl[tid] = st[tid * 2 + 1]; }
    if (tid < 3) fbl[tid] = fb[tid];
    __syncthreads();
    int e = blockIdx.x * 256 + tid;
    int b = e >> 16, px = e & 65535;
    float a0 = fbl[0], a1 = fbl[1], a2 = fbl[2];
    const u16* rowp = y5 + (size_t)e * 64;
    for (int cb = 0; cb < 8; cb++) {
        uint4 u = *reinterpret_cast<const uint4*>(rowp + cb * 8);
        unsigned wd[4] = {u.x, u.y, u.z, u.w};
#pragma unroll
        for (int q = 0; q < 4; q++) {
            int c = cb * 8 + 2 * q;
            float v0 = fmaxf(bfu2f(wd[q] & 0xffffu) * sl[c] + tl[c], 0.f);
            float v1 = fmaxf(bfu2f(wd[q] >> 16) * sl[c + 1] + tl[c + 1], 0.f);
            a0 += v0 * fwl[c] + v1 * fwl[c + 1];
            a1 += v0 * fwl[64 + c] + v1 * fwl[64 + c + 1];
            a2 += v0 * fwl[128 + c] + v1 * fwl[128 + c + 1];
        }
    }
    out[(b * 3 + 0) * NPX + px] = a0;
    out[(b * 3 + 1) * NPX + px] = a1;
    out[(b * 3 + 2) * NPX + px] = a2;
}

extern "C" void kernel_launch(void* const* d_in, const int* in_sizes, int n_in,
                              void* d_out, int out_size, void* d_ws, size_t ws_size,
                              hipStream_t stream) {
    (void)in_sizes; (void)n_in; (void)out_size; (void)ws_size;
    const float* image   = (const float*)d_in[0];
    const float* message = (const float*)d_in[1];
    const float* w0      = (const float*)d_in[2];
    const float* g0      = (const float*)d_in[4];
    const float* be0     = (const float*)d_in[5];
    const float* wsv     = (const float*)d_in[6];
    const float* gs      = (const float*)d_in[8];
    const float* bes     = (const float*)d_in[9];
    const float* acw     = (const float*)d_in[10];
    const float* acg     = (const float*)d_in[12];
    const float* acbe    = (const float*)d_in[13];
    const float* fw      = (const float*)d_in[14];
    const float* fb      = (const float*)d_in[15];
    float* out = (float*)d_out;

    // workspace layout — total 134,974,336 B (~128.7 MiB)
    u16* XA   = (u16*)d_ws;                // 33,554,432 u16 (64 MiB)
    u16* XB   = XA + 33554432;             // 33,554,432 u16 (64 MiB)
    // low-pass scratch ALIASES XB (dead before conv2 writes XB)
    float* Yb = (float*)XB;                // 1,241,088 f  [kxi][ch][y][2]
    float* Wb = Yb + 1241088;              // 1,241,088 f  [ch][y][kxi][2]
    float* LP = Wb + 1241088;              // 1,572,864 f
    u16* WPa  = XB + 33554432;             // 110,592 u16
    u16* WP5  = WPa + 110592;              // 55,296 u16
    float* TW   = (float*)(WP5 + 55296);   // 512 f
    float* D2T  = TW + 512;                // 25,856 f  [kxi][d]
    float* PART = D2T + 25856;             // 32,768 f
    float* ST   = PART + 32768;            // 128 f
    float* DLT  = ST + 128;                // 480 f
    float* G    = DLT + 480;               // 24,576 f
    float* WSm  = G + 24576;               // 17,280 f
    float* Mt   = WSm + 17280;             // 4,608 f

    dim3 cgrid(16, 16, 8);

    k_tables<<<103, 256, 0, stream>>>(TW, D2T);
    k_wprep<<<216, 64, 0, stream>>>(wsv, WPa);
    k_wprep5<<<108, 64, 0, stream>>>(acw, WP5);
    k_wsum<<<1, 256, 0, stream>>>(acw, WSm);
    k_msgM<<<8, 256, 0, stream>>>(message, WSm, Mt);

    k_lp1<<<dim3(128, 24), 256, 0, stream>>>(image, TW, Yb);
    k_lp2<<<dim3(101, 6), 256, 0, stream>>>(Yb, D2T, Wb);
    k_lp3<<<dim3(256, 24), 256, 0, stream>>>(Wb, TW, LP);

    // conv1 -> XA (raw NHWC bf16)
    k_conv1<<<cgrid, 256, 0, stream>>>(LP, w0, XA);
    k_stats<<<256, 256, 0, stream>>>(XA, PART);
    k_finalize<<<1, 256, 0, stream>>>(PART, g0, be0, ST);
    // conv2: XA -> XB (overwrites dead LP scratch)
    k_cmfma<0><<<cgrid, 256, 0, stream>>>(XA, WPa + 0 * 36864, ST, nullptr, nullptr, nullptr, nullptr, XB);
    k_stats<<<256, 256, 0, stream>>>(XB, PART);
    k_finalize<<<1, 256, 0, stream>>>(PART, gs + 0, bes + 0, ST);
    // conv3: XB -> XA
    k_cmfma<0><<<cgrid, 256, 0, stream>>>(XB, WPa + 1 * 36864, ST, nullptr, nullptr, nullptr, nullptr, XA);
    k_stats<<<256, 256, 0, stream>>>(XA, PART);
    k_finalize<<<1, 256, 0, stream>>>(PART, gs + 64, bes + 64, ST);
    // conv4: XA -> XB (raw y4)
    k_cmfma<0><<<cgrid, 256, 0, stream>>>(XA, WPa + 2 * 36864, ST, nullptr, nullptr, nullptr, nullptr, XB);
    k_stats<<<256, 256, 0, stream>>>(XB, PART);
    k_finalize<<<1, 256, 0, stream>>>(PART, gs + 128, bes + 128, ST);
    // watermark deltas from y4 ch0
    k_wmG<<<dim3(8, 8), 256, 0, stream>>>(XB, ST, TW, G);
    k_wmC<<<8, 256, 0, stream>>>(G, message, TW, DLT);
    // conv5 (enc staged from y4 + corr; img; msg via M term) -> XA
    k_cmfma<1><<<cgrid, 256, 0, stream>>>(XB, WP5, ST, image, DLT, TW, Mt, XA);
    k_stats<<<256, 256, 0, stream>>>(XA, PART);
    k_finalize<<<1, 256, 0, stream>>>(PART, acg, acbe, ST);
    // final 1x1 conv
    k_final<<<2048, 256, 0, stream>>>(XA, ST, fw, fb, out);
}

// Round 7
// 731.692 us; speedup vs baseline: 4.1274x; 1.2090x over previous
//
#include <hip/hip_runtime.h>
#include <math.h>

// ---------------------------------------------------------------------------
// Encoder_75557064671564 — MFMA bf16 conv stack, NHWC intermediates.
//
// ROUND-7: identical to round-6 source (container infra failure; no kernel
// signal). k_lp1/k_lp3 use complex-rotation recurrence instead of scattered
// fp64 LDS table reads (round-5 profile: 3.5e7 bank conflicts on k_lp1).
// Workspace: 134,978,432 B (~128.7 MiB); LP scratch aliases XB.
// ---------------------------------------------------------------------------

#define NPX 65536
typedef unsigned short u16;
typedef __bf16 bfrag_t __attribute__((ext_vector_type(8)));
typedef float f32x4 __attribute__((ext_vector_type(4)));

__constant__ int WM_R_[30] = {124, 125,125,125,125,125, 126,126,126,126,126,126,126,
                              127,127,127,127,127,127,127,
                              128,128,128,128,128,128,128,128,128, 129};
__constant__ int WM_C_[30] = {128, 126,127,128,129,130, 125,126,127,128,129,130,131,
                              125,126,127,128,129,130,131,
                              124,125,126,127,128,129,130,131,132, 125};

__device__ __forceinline__ float bfu2f(unsigned int bits) {
    return __uint_as_float(bits << 16);
}
__device__ __forceinline__ u16 f2bu(float f) {
    unsigned int u = __float_as_uint(f);
    u += 0x7fffu + ((u >> 16) & 1u);
    return (u16)(u >> 16);
}

// ---------------- tables ----------------
__global__ void k_tables(float* __restrict__ tw, float* __restrict__ d2t,
                         double* __restrict__ twd64) {
    int idx = blockIdx.x * 256 + threadIdx.x;
    if (idx < 256) {
        double ang = -2.0 * M_PI * (double)idx / 256.0;
        tw[idx]       = (float)cos(ang);
        tw[256 + idx] = (float)sin(ang);
        twd64[idx]       = cos(ang);
        twd64[256 + idx] = sin(ang);
    }
    int q = idx - 256;
    if (q >= 0 && q < 256 * 101) {
        int d = q / 101, kxi = q - d * 101;
        int vx = (kxi <= 50) ? kxi : kxi - 101;
        int r2 = 2500 - vx * vx;
        int L = 0;
        while ((L + 1) * (L + 1) <= r2) L++;
        double s = 1.0;
        for (int v = 1; v <= L; v++) s += 2.0 * cos(2.0 * M_PI * (double)(v * d) / 256.0);
        d2t[kxi * 256 + d] = (float)(s / 256.0);
    }
}

// ---------------- low-pass chain (fp64, rotation recurrence) ----------------
__global__ __launch_bounds__(256) void k_lp1(const float* __restrict__ img,
        const double* __restrict__ twd64, float* __restrict__ Y) {
    __shared__ double rowd[4][256];
    int y0 = blockIdx.x * 4, ch = blockIdx.y, tid = threadIdx.x;
#pragma unroll
    for (int r = 0; r < 4; r++)
        rowd[r][tid] = (double)img[ch * NPX + (y0 + r) * 256 + tid];
    __syncthreads();
    int kxi = tid & 127, rg = tid >> 7;
    if (kxi >= 101) return;
    int kx = (kxi <= 50) ? kxi : kxi + 155;
    double cr = twd64[kx], ci = twd64[256 + kx];   // step e^{-2pi i kx/256}
    double wr = 1.0, wi = 0.0;
    double a0r = 0, a0i = 0, a1r = 0, a1i = 0;
    const double* r0 = rowd[2 * rg];
    const double* r1 = rowd[2 * rg + 1];
    for (int x = 0; x < 256; x++) {
        double v0 = r0[x], v1 = r1[x];
        a0r += v0 * wr; a0i += v0 * wi;
        a1r += v1 * wr; a1i += v1 * wi;
        double t = wr * cr - wi * ci;
        wi = wr * ci + wi * cr;
        wr = t;
    }
    int y = y0 + 2 * rg;
    int o = ((kxi * 24 + ch) * 256 + y) * 2;
    Y[o]     = (float)a0r; Y[o + 1] = (float)a0i;
    Y[o + 2] = (float)a1r; Y[o + 3] = (float)a1i;
}

__global__ __launch_bounds__(256) void k_lp2(const float* __restrict__ Y,
        const float* __restrict__ d2t, float* __restrict__ W) {
    __shared__ double Ys[4][256][2];   // 16 KB
    __shared__ double Dc[256];         // 2 KB
    int kxi = blockIdx.x, chg = blockIdx.y, tid = threadIdx.x;
    const float* src = Y + (size_t)(kxi * 24 + chg * 4) * 512;
    double* ysf = (double*)Ys;
    for (int i = tid; i < 2048; i += 256) ysf[i] = (double)src[i];
    Dc[tid] = (double)d2t[kxi * 256 + tid];
    __syncthreads();
    int cs = tid >> 6, y4 = tid & 63;
    double wr[4] = {0, 0, 0, 0}, wi[4] = {0, 0, 0, 0};
    for (int yp = 0; yp < 256; yp++) {
        double yr = Ys[cs][yp][0], yi = Ys[cs][yp][1];
        double D0 = Dc[(y4 - yp) & 255];
        double D1 = Dc[(y4 + 64 - yp) & 255];
        double D2 = Dc[(y4 + 128 - yp) & 255];
        double D3 = Dc[(y4 + 192 - yp) & 255];
        wr[0] += D0 * yr; wi[0] += D0 * yi;
        wr[1] += D1 * yr; wi[1] += D1 * yi;
        wr[2] += D2 * yr; wi[2] += D2 * yi;
        wr[3] += D3 * yr; wi[3] += D3 * yi;
    }
    int ch = chg * 4 + cs;
#pragma unroll
    for (int k = 0; k < 4; k++) {
        int y = y4 + 64 * k;
        int o = ((ch * 256 + y) * 101 + kxi) * 2;
        W[o] = (float)wr[k]; W[o + 1] = (float)wi[k];
    }
}

__global__ __launch_bounds__(256) void k_lp3(const float* __restrict__ W,
        const double* __restrict__ twd64, float* __restrict__ lp) {
    __shared__ double wsr[101], wsi[101];
    int y = blockIdx.x, ch = blockIdx.y, x = threadIdx.x;
    if (x < 101) {
        int kxi = (x < 50) ? (x + 51) : (x - 50);   // j=x -> kx=j-50
        wsr[x] = (double)W[((ch * 256 + y) * 101 + kxi) * 2];
        wsi[x] = (double)W[((ch * 256 + y) * 101 + kxi) * 2 + 1];
    }
    __syncthreads();
    // start w = e^{+2pi i * 50 x/256}; step = e^{-2pi i x/256}
    int t0 = (50 * x) & 255;
    double wr = twd64[t0], wi = -twd64[256 + t0];
    double cr = twd64[x], ci = twd64[256 + x];
    double acc = 0.0;
    for (int j = 0; j < 101; j++) {
        acc += wsr[j] * wr + wsi[j] * wi;
        double t = wr * cr - wi * ci;
        wi = wr * ci + wi * cr;
        wr = t;
    }
    acc *= (1.0 / 256.0);
    acc = floor(fmin(fmax(acc, 0.0), 255.0)) / 255.0;
    lp[ch * NPX + y * 256 + x] = (float)acc;
}

// ---------------- conv1: CIN=3, fp32 VALU, NHWC bf16 out ----------------
__global__ __launch_bounds__(256, 2) void k_conv1(
    const float* __restrict__ lp, const float* __restrict__ w0,
    u16* __restrict__ out) {
    __shared__ float wl[3][9][64];
    __shared__ float al[3][18][18];
    int tid = threadIdx.x;
    int b = blockIdx.z, r0 = blockIdx.y * 16, c0 = blockIdx.x * 16;
    int ocg = tid >> 5, pxg = tid & 31;
    int row = pxg >> 1, chof = (pxg & 1) * 8;
    int oc0 = ocg * 8;
    float acc[8][8];
#pragma unroll
    for (int o = 0; o < 8; o++)
#pragma unroll
        for (int p = 0; p < 8; p++) acc[o][p] = 0.f;
    for (int idx = tid; idx < 1728; idx += 256) {
        int ic = idx / 576, rem = idx - ic * 576;
        int tap = rem >> 6, oc = rem & 63;
        wl[ic][tap][oc] = w0[(oc * 3 + ic) * 9 + tap];
    }
    for (int idx = tid; idx < 972; idx += 256) {
        int ic = idx / 324, rem = idx - ic * 324;
        int ly = rem / 18, lx = rem - ly * 18;
        int gy = r0 - 1 + ly, gx = c0 - 1 + lx;
        float v = 0.f;
        if ((unsigned)gy < 256u && (unsigned)gx < 256u)
            v = lp[(b * 3 + ic) * NPX + gy * 256 + gx];
        al[ic][ly][lx] = v;
    }
    __syncthreads();
    for (int ic = 0; ic < 3; ic++) {
        float areg[3][10];
#pragma unroll
        for (int di = 0; di < 3; di++)
#pragma unroll
            for (int xx = 0; xx < 10; xx++) areg[di][xx] = al[ic][row + di][chof + xx];
#pragma unroll
        for (int tap = 0; tap < 9; tap++) {
            const int di = tap / 3, dj = tap % 3;
            float wv[8];
#pragma unroll
            for (int o = 0; o < 8; o++) wv[o] = wl[ic][tap][oc0 + o];
#pragma unroll
            for (int o = 0; o < 8; o++)
#pragma unroll
                for (int p = 0; p < 8; p++)
                    acc[o][p] = fmaf(wv[o], areg[di][dj + p], acc[o][p]);
        }
    }
#pragma unroll
    for (int p = 0; p < 8; p++) {
        unsigned wd[4];
#pragma unroll
        for (int q = 0; q < 4; q++)
            wd[q] = (unsigned)f2bu(acc[2 * q][p]) | ((unsigned)f2bu(acc[2 * q + 1][p]) << 16);
        size_t addr = ((size_t)((b * 256 + r0 + row) * 256 + c0 + chof + p)) * 64 + oc0;
        uint4 vv; vv.x = wd[0]; vv.y = wd[1]; vv.z = wd[2]; vv.w = wd[3];
        *reinterpret_cast<uint4*>(out + addr) = vv;
    }
}

// ---------------- weight packing ----------------
__global__ void k_wprep(const float* __restrict__ wsv, u16* __restrict__ wp) {
    int bid = blockIdx.x;                  // 216 = 3 convs * 72
    int conv = bid / 72, fg = bid % 72;
    int icc = fg / 36, t2 = fg % 36, tap = t2 / 4, ocb = t2 % 4;
    int l = threadIdx.x;                   // 64
    int oc = ocb * 16 + (l & 15);
    unsigned wd[4];
#pragma unroll
    for (int q = 0; q < 4; q++) {
        int ic0 = icc * 32 + (l >> 4) * 8 + 2 * q;
        float v0 = wsv[conv * 36864 + (oc * 64 + ic0) * 9 + tap];
        float v1 = wsv[conv * 36864 + (oc * 64 + ic0 + 1) * 9 + tap];
        wd[q] = (unsigned)f2bu(v0) | ((unsigned)f2bu(v1) << 16);
    }
    uint4 vv; vv.x = wd[0]; vv.y = wd[1]; vv.z = wd[2]; vv.w = wd[3];
    reinterpret_cast<uint4*>(wp)[conv * 4608 + fg * 64 + l] = vv;
}

__global__ void k_wprep5(const float* __restrict__ acw, u16* __restrict__ wp5) {
    int fg = blockIdx.x;                   // 108
    int icc = fg / 36, t2 = fg % 36, tap = t2 / 4, ocb = t2 % 4;
    int l = threadIdx.x;
    int oc = ocb * 16 + (l & 15);
    unsigned wd[4];
#pragma unroll
    for (int q = 0; q < 4; q++) {
        unsigned out2 = 0;
#pragma unroll
        for (int h = 0; h < 2; h++) {
            int icp = icc * 32 + (l >> 4) * 8 + 2 * q + h;
            float v = 0.f;
            if (icp < 67) v = acw[(oc * 97 + 30 + icp) * 9 + tap];
            out2 |= ((unsigned)f2bu(v)) << (16 * h);
        }
        wd[q] = out2;
    }
    uint4 vv; vv.x = wd[0]; vv.y = wd[1]; vv.z = wd[2]; vv.w = wd[3];
    reinterpret_cast<uint4*>(wp5)[fg * 64 + l] = vv;
}

__global__ void k_wsum(const float* __restrict__ acw, float* __restrict__ wsum) {
    for (int e = threadIdx.x; e < 17280; e += 256) {
        int oc = e / 270, r2 = e % 270, ic = r2 / 9, cls = r2 % 9;
        int cy = cls / 3, cx = cls % 3;
        int dil = (cy == 0) ? 1 : 0, dih = (cy == 2) ? 1 : 2;
        int djl = (cx == 0) ? 1 : 0, djh = (cx == 2) ? 1 : 2;
        float s = 0.f;
        for (int di = dil; di <= dih; di++)
            for (int dj = djl; dj <= djh; dj++)
                s += acw[(oc * 97 + ic) * 9 + di * 3 + dj];
        wsum[e] = s;
    }
}

__global__ void k_msgM(const float* __restrict__ msg, const float* __restrict__ wsum,
                       float* __restrict__ M) {
    int b = blockIdx.x;
    for (int t = threadIdx.x; t < 576; t += 256) {
        int oc = t / 9, cls = t % 9;
        float s = 0.f;
        for (int ic = 0; ic < 30; ic++)
            s += msg[b * 30 + ic] * wsum[oc * 270 + ic * 9 + cls];
        M[b * 576 + t] = s;
    }
}

// ---------------- MFMA conv3x3 (convs 2-5) ----------------
template <int MODE>
__global__ __launch_bounds__(256, 2) void k_cmfma(
    const u16* __restrict__ src, const u16* __restrict__ wp,
    const float* __restrict__ st, const float* __restrict__ img,
    const float* __restrict__ dlt, const float* __restrict__ tw,
    const float* __restrict__ Mterm, u16* __restrict__ out) {
    const int NC = (MODE == 0) ? 2 : 3;
    __shared__ __align__(16) u16 ain[4 * 324 * 8];   // [kb][ly*18+lx][j]
    __shared__ float sst[128];
    __shared__ float twl[512];
    __shared__ float dl[60];
    __shared__ float Ml[576];

    int tid = threadIdx.x;
    int wv = tid >> 6, l = tid & 63;
    int b = blockIdx.z, y0 = blockIdx.y * 16, x0 = blockIdx.x * 16;

    if (tid < 128) sst[tid] = st[tid];
    if (MODE == 1) {
        twl[tid] = tw[tid]; twl[tid + 256] = tw[tid + 256];
        if (tid < 60) dl[tid] = dlt[b * 60 + tid];
        for (int i = tid; i < 576; i += 256) Ml[i] = Mterm[b * 576 + i];
    }

    f32x4 acc[4][4];
#pragma unroll
    for (int nt = 0; nt < 4; nt++)
#pragma unroll
        for (int ob = 0; ob < 4; ob++) acc[nt][ob] = (f32x4)(0.f);

    const uint4* wq = reinterpret_cast<const uint4*>(wp);
    const uint4* ap = reinterpret_cast<const uint4*>(ain);
    const int bl = (l >> 4) * 324 + (l & 15);
    const int wv4 = wv * 4;

#pragma unroll 1
    for (int icc = 0; icc < NC; icc++) {
        __syncthreads();
        if (MODE == 1 && icc == 2) {
            for (int i = tid; i < 1296; i += 256) {
                int kb = i / 324, r = i - kb * 324;
                int ly = r / 18, lx = r - ly * 18;
                int gy = y0 - 1 + ly, gx = x0 - 1 + lx;
                uint4 pk; pk.x = 0; pk.y = 0; pk.z = 0; pk.w = 0;
                if (kb == 0 && (unsigned)gy < 256u && (unsigned)gx < 256u) {
                    float v0 = img[(b * 3 + 0) * NPX + gy * 256 + gx];
                    float v1 = img[(b * 3 + 1) * NPX + gy * 256 + gx];
                    float v2 = img[(b * 3 + 2) * NPX + gy * 256 + gx];
                    pk.x = (unsigned)f2bu(v0) | ((unsigned)f2bu(v1) << 16);
                    pk.y = (unsigned)f2bu(v2);
                }
                reinterpret_cast<uint4*>(ain)[i] = pk;
            }
        } else {
            for (int i = tid; i < 1296; i += 256) {
                int kb = i / 324, r = i - kb * 324;
                int ly = r / 18, lx = r - ly * 18;
                int gy = y0 - 1 + ly, gx = x0 - 1 + lx;
                uint4 pk; pk.x = 0; pk.y = 0; pk.z = 0; pk.w = 0;
                if ((unsigned)gy < 256u && (unsigned)gx < 256u) {
                    size_t gaddr = ((size_t)((b * 256 + gy) * 256 + gx)) * 64 + icc * 32 + kb * 8;
                    uint4 u = *reinterpret_cast<const uint4*>(src + gaddr);
                    unsigned wd[4] = {u.x, u.y, u.z, u.w};
                    float f[8];
                    int cb = icc * 32 + kb * 8;
#pragma unroll
                    for (int q = 0; q < 4; q++) {
                        f[2 * q]     = fmaxf(bfu2f(wd[q] & 0xffffu) * sst[2 * (cb + 2 * q)] + sst[2 * (cb + 2 * q) + 1], 0.f);
                        f[2 * q + 1] = fmaxf(bfu2f(wd[q] >> 16)     * sst[2 * (cb + 2 * q + 1)] + sst[2 * (cb + 2 * q + 1) + 1], 0.f);
                    }
                    if (MODE == 1 && icc == 0 && kb == 0) {
                        float corr = 0.f;
#pragma unroll
                        for (int p = 0; p < 30; p++) {
                            int t = (WM_R_[p] * gy + WM_C_[p] * gx) & 255;
                            corr += dl[2 * p] * twl[t] + dl[2 * p + 1] * twl[256 + t];
                        }
                        f[0] += corr * (1.0f / 65536.0f);
                    }
                    unsigned po[4];
#pragma unroll
                    for (int q = 0; q < 4; q++)
                        po[q] = (unsigned)f2bu(f[2 * q]) | ((unsigned)f2bu(f[2 * q + 1]) << 16);
                    pk.x = po[0]; pk.y = po[1]; pk.z = po[2]; pk.w = po[3];
                }
                reinterpret_cast<uint4*>(ain)[i] = pk;
            }
        }
        __syncthreads();

        uint4 a0, a1, a2, a3, n0, n1, n2, n3;
        {
            const uint4* q = wq + ((icc * 9 + 0) * 256 + l);
            a0 = q[0]; a1 = q[64]; a2 = q[128]; a3 = q[192];
        }
#pragma unroll
        for (int tap = 0; tap < 9; tap++) {
            if (tap < 8) {
                const uint4* q = wq + ((icc * 9 + tap + 1) * 256 + l);
                n0 = q[0]; n1 = q[64]; n2 = q[128]; n3 = q[192];
            }
            const int di = tap / 3, dj = tap % 3;
#pragma unroll
            for (int nt = 0; nt < 4; nt++) {
                uint4 braw = ap[bl + (wv4 + nt + di) * 18 + dj];
                bfrag_t bf = __builtin_bit_cast(bfrag_t, braw);
                acc[nt][0] = __builtin_amdgcn_mfma_f32_16x16x32_bf16(
                    __builtin_bit_cast(bfrag_t, a0), bf, acc[nt][0], 0, 0, 0);
                acc[nt][1] = __builtin_amdgcn_mfma_f32_16x16x32_bf16(
                    __builtin_bit_cast(bfrag_t, a1), bf, acc[nt][1], 0, 0, 0);
                acc[nt][2] = __builtin_amdgcn_mfma_f32_16x16x32_bf16(
                    __builtin_bit_cast(bfrag_t, a2), bf, acc[nt][2], 0, 0, 0);
                acc[nt][3] = __builtin_amdgcn_mfma_f32_16x16x32_bf16(
                    __builtin_bit_cast(bfrag_t, a3), bf, acc[nt][3], 0, 0, 0);
            }
            a0 = n0; a1 = n1; a2 = n2; a3 = n3;
        }
    }

    int x = x0 + (l & 15);
    int ocq = (l >> 4) * 4;
    int clsx = (x == 0) ? 0 : ((x == 255) ? 2 : 1);
#pragma unroll
    for (int nt = 0; nt < 4; nt++) {
        int y = y0 + wv4 + nt;
#pragma unroll
        for (int ob = 0; ob < 4; ob++) {
            int oc = ob * 16 + ocq;
            float v0 = acc[nt][ob][0], v1 = acc[nt][ob][1];
            float v2 = acc[nt][ob][2], v3 = acc[nt][ob][3];
            if (MODE == 1) {
                int cls = ((y == 0) ? 0 : ((y == 255) ? 6 : 3)) + clsx;
                v0 += Ml[(oc + 0) * 9 + cls];
                v1 += Ml[(oc + 1) * 9 + cls];
                v2 += Ml[(oc + 2) * 9 + cls];
                v3 += Ml[(oc + 3) * 9 + cls];
            }
            uint2 pk;
            pk.x = (unsigned)f2bu(v0) | ((unsigned)f2bu(v1) << 16);
            pk.y = (unsigned)f2bu(v2) | ((unsigned)f2bu(v3) << 16);
            size_t addr = ((size_t)((b * 256 + y) * 256 + x)) * 64 + oc;
            *reinterpret_cast<uint2*>(out + addr) = pk;
        }
    }
}

// ---------------- BN stats over NHWC raw bf16 ----------------
__global__ void k_stats(const u16* __restrict__ y, float* __restrict__ part) {
    __shared__ float red[2048];
    int blk = blockIdx.x, tid = threadIdx.x;
    int j = tid & 7, g = tid >> 3;
    float s1[8], s2[8];
#pragma unroll
    for (int k = 0; k < 8; k++) { s1[k] = 0.f; s2[k] = 0.f; }
    for (int it = 0; it < 64; it++) {
        int px = blk * 2048 + it * 32 + g;
        uint4 u = *reinterpret_cast<const uint4*>(y + (size_t)px * 64 + j * 8);
        unsigned wd[4] = {u.x, u.y, u.z, u.w};
#pragma unroll
        for (int q = 0; q < 4; q++) {
            float v0 = bfu2f(wd[q] & 0xffffu), v1 = bfu2f(wd[q] >> 16);
            s1[2 * q] += v0; s2[2 * q] += v0 * v0;
            s1[2 * q + 1] += v1; s2[2 * q + 1] += v1 * v1;
        }
    }
#pragma unroll
    for (int k = 0; k < 8; k++) red[tid * 8 + k] = s1[k];
    __syncthreads();
    if (tid < 64) {
        float a = 0.f;
        for (int gg = 0; gg < 32; gg++) a += red[gg * 64 + tid];
        part[blk * 128 + tid * 2] = a;
    }
    __syncthreads();
#pragma unroll
    for (int k = 0; k < 8; k++) red[tid * 8 + k] = s2[k];
    __syncthreads();
    if (tid < 64) {
        float a = 0.f;
        for (int gg = 0; gg < 32; gg++) a += red[gg * 64 + tid];
        part[blk * 128 + tid * 2 + 1] = a;
    }
}

__global__ void k_finalize(const float* __restrict__ part, const float* __restrict__ g,
                           const float* __restrict__ be, float* __restrict__ st) {
    __shared__ double d1[256], d2[256];
    int tid = threadIdx.x;
    int c = tid >> 2, q = tid & 3;
    double S1 = 0.0, S2 = 0.0;
    for (int k = 0; k < 64; k++) {
        int blk = q * 64 + k;
        S1 += (double)part[blk * 128 + c * 2];
        S2 += (double)part[blk * 128 + c * 2 + 1];
    }
    d1[tid] = S1; d2[tid] = S2;
    __syncthreads();
    if (tid < 64) {
        double T1 = 0.0, T2 = 0.0;
        for (int qq = 0; qq < 4; qq++) { T1 += d1[tid * 4 + qq]; T2 += d2[tid * 4 + qq]; }
        const double Nn = 524288.0;
        double mean = T1 / Nn;
        double var = T2 / Nn - mean * mean;
        float s = (float)((double)g[tid] / sqrt(var + 1e-5));
        float t = (float)((double)be[tid] - mean * (double)s);
        st[tid * 2] = s; st[tid * 2 + 1] = t;
    }
}

// ---------------- watermark coefficient passes ----------------
__global__ void k_wmG(const u16* __restrict__ y4, const float* __restrict__ st,
                      const float* __restrict__ tw, float* __restrict__ G) {
    __shared__ float twl[512];
    __shared__ float red[256][12];
    int b = blockIdx.x, xg = blockIdx.y, tid = threadIdx.x;
    twl[tid] = tw[tid]; twl[tid + 256] = tw[tid + 256];
    __syncthreads();
    int xs = tid & 31, x = xg * 32 + xs, yg = tid >> 5;
    float s0 = st[0], t0 = st[1];
    float gr[6], gi[6];
#pragma unroll
    for (int r = 0; r < 6; r++) { gr[r] = 0.f; gi[r] = 0.f; }
    for (int yy = 0; yy < 32; yy++) {
        int y = yg * 32 + yy;
        float v = fmaxf(bfu2f((unsigned)y4[((size_t)((b * 256 + y) * 256 + x)) * 64]) * s0 + t0, 0.f);
#pragma unroll
        for (int r = 0; r < 6; r++) {
            int t = ((124 + r) * y) & 255;
            gr[r] += v * twl[t];
            gi[r] += v * twl[256 + t];
        }
    }
#pragma unroll
    for (int r = 0; r < 6; r++) { red[tid][2 * r] = gr[r]; red[tid][2 * r + 1] = gi[r]; }
    __syncthreads();
    for (int e = tid; e < 384; e += 256) {
        int xs2 = e & 31, c = e >> 5;
        float s = 0.f;
        for (int g = 0; g < 8; g++) s += red[g * 32 + xs2][c];
        int r = c >> 1, ri = c & 1;
        G[((b * 6 + r) * 256 + (xg * 32 + xs2)) * 2 + ri] = s;
    }
}

__global__ void k_wmC(const float* __restrict__ G, const float* __restrict__ msg,
                      const float* __restrict__ tw, float* __restrict__ dlt) {
    __shared__ float twl[512];
    __shared__ float fr[256], fi[256];
    int b = blockIdx.x, tid = threadIdx.x;
    twl[tid] = tw[tid]; twl[tid + 256] = tw[tid + 256];
    __syncthreads();
    int p = tid >> 3, part = tid & 7;
    float Fr = 0.f, Fi = 0.f;
    if (p < 30) {
        int rp = WM_R_[p] - 124, c = WM_C_[p];
        for (int xx = part * 32; xx < part * 32 + 32; xx++) {
            float gr = G[((b * 6 + rp) * 256 + xx) * 2];
            float gi = G[((b * 6 + rp) * 256 + xx) * 2 + 1];
            int u = (c * xx) & 255;
            Fr += gr * twl[u] - gi * twl[256 + u];
            Fi += gr * twl[256 + u] + gi * twl[u];
        }
    }
    fr[tid] = Fr; fi[tid] = Fi;
    __syncthreads();
    if (p < 30 && part == 0) {
        float sr = 0.f, si = 0.f;
        for (int k = 0; k < 8; k++) { sr += fr[p * 8 + k]; si += fi[p * 8 + k]; }
        float m = msg[b * 30 + p];
        dlt[b * 60 + p * 2]     = m - sr;
        dlt[b * 60 + p * 2 + 1] = m - si;
    }
}

// ---------------- final 1x1 conv, NHWC in, CHW fp32 out ----------------
__global__ void k_final(const u16* __restrict__ y5, const float* __restrict__ st,
                        const float* __restrict__ fw, const float* __restrict__ fb,
                        float* __restrict__ out) {
    __shared__ float fwl[192];
    __shared__ float sl[64], tl[64];
    __shared__ float fbl[3];
    int tid = threadIdx.x;
    if (tid < 192) fwl[tid] = fw[tid];
    if (tid < 64) { sl[tid] = st[tid * 2]; tl[tid] = st[tid * 2 + 1]; }
    if (tid < 3) fbl[tid] = fb[tid];
    __syncthreads();
    int e = blockIdx.x * 256 + tid;
    int b = e >> 16, px = e & 65535;
    float a0 = fbl[0], a1 = fbl[1], a2 = fbl[2];
    const u16* rowp = y5 + (size_t)e * 64;
    for (int cb = 0; cb < 8; cb++) {
        uint4 u = *reinterpret_cast<const uint4*>(rowp + cb * 8);
        unsigned wd[4] = {u.x, u.y, u.z, u.w};
#pragma unroll
        for (int q = 0; q < 4; q++) {
            int c = cb * 8 + 2 * q;
            float v0 = fmaxf(bfu2f(wd[q] & 0xffffu) * sl[c] + tl[c], 0.f);
            float v1 = fmaxf(bfu2f(wd[q] >> 16) * sl[c + 1] + tl[c + 1], 0.f);
            a0 += v0 * fwl[c] + v1 * fwl[c + 1];
            a1 += v0 * fwl[64 + c] + v1 * fwl[64 + c + 1];
            a2 += v0 * fwl[128 + c] + v1 * fwl[128 + c + 1];
        }
    }
    out[(b * 3 + 0) * NPX + px] = a0;
    out[(b * 3 + 1) * NPX + px] = a1;
    out[(b * 3 + 2) * NPX + px] = a2;
}

extern "C" void kernel_launch(void* const* d_in, const int* in_sizes, int n_in,
                              void* d_out, int out_size, void* d_ws, size_t ws_size,
                              hipStream_t stream) {
    (void)in_sizes; (void)n_in; (void)out_size; (void)ws_size;
    const float* image   = (const float*)d_in[0];
    const float* message = (const float*)d_in[1];
    const float* w0      = (const float*)d_in[2];
    const float* g0      = (const float*)d_in[4];
    const float* be0     = (const float*)d_in[5];
    const float* wsv     = (const float*)d_in[6];
    const float* gs      = (const float*)d_in[8];
    const float* bes     = (const float*)d_in[9];
    const float* acw     = (const float*)d_in[10];
    const float* acg     = (const float*)d_in[12];
    const float* acbe    = (const float*)d_in[13];
    const float* fw      = (const float*)d_in[14];
    const float* fb      = (const float*)d_in[15];
    float* out = (float*)d_out;

    // workspace layout — total 134,978,432 B (~128.7 MiB)
    u16* XA   = (u16*)d_ws;                // 33,554,432 u16 (64 MiB)
    u16* XB   = XA + 33554432;             // 33,554,432 u16 (64 MiB)
    // low-pass scratch ALIASES XB (dead before conv2 writes XB)
    float* Yb = (float*)XB;                // 1,241,088 f  [kxi][ch][y][2]
    float* Wb = Yb + 1241088;              // 1,241,088 f  [ch][y][kxi][2]
    float* LP = Wb + 1241088;              // 1,572,864 f
    u16* WPa  = XB + 33554432;             // 110,592 u16
    u16* WP5  = WPa + 110592;              // 55,296 u16
    float* TW   = (float*)(WP5 + 55296);   // 512 f
    float* D2T  = TW + 512;                // 25,856 f  [kxi][d]
    float* PART = D2T + 25856;             // 32,768 f
    float* ST   = PART + 32768;            // 128 f
    float* DLT  = ST + 128;                // 480 f
    float* G    = DLT + 480;               // 24,576 f
    float* WSm  = G + 24576;               // 17,280 f
    float* Mt   = WSm + 17280;             // 4,608 f
    double* TW64 = (double*)(Mt + 4608);   // 512 d (byte off 134,974,336 %8==0)

    dim3 cgrid(16, 16, 8);

    k_tables<<<103, 256, 0, stream>>>(TW, D2T, TW64);
    k_wprep<<<216, 64, 0, stream>>>(wsv, WPa);
    k_wprep5<<<108, 64, 0, stream>>>(acw, WP5);
    k_wsum<<<1, 256, 0, stream>>>(acw, WSm);
    k_msgM<<<8, 256, 0, stream>>>(message, WSm, Mt);

    k_lp1<<<dim3(64, 24), 256, 0, stream>>>(image, TW64, Yb);
    k_lp2<<<dim3(101, 6), 256, 0, stream>>>(Yb, D2T, Wb);
    k_lp3<<<dim3(256, 24), 256, 0, stream>>>(Wb, TW64, LP);

    // conv1 -> XA (raw NHWC bf16)
    k_conv1<<<cgrid, 256, 0, stream>>>(LP, w0, XA);
    k_stats<<<256, 256, 0, stream>>>(XA, PART);
    k_finalize<<<1, 256, 0, stream>>>(PART, g0, be0, ST);
    // conv2: XA -> XB (overwrites dead LP scratch)
    k_cmfma<0><<<cgrid, 256, 0, stream>>>(XA, WPa + 0 * 36864, ST, nullptr, nullptr, nullptr, nullptr, XB);
    k_stats<<<256, 256, 0, stream>>>(XB, PART);
    k_finalize<<<1, 256, 0, stream>>>(PART, gs + 0, bes + 0, ST);
    // conv3: XB -> XA
    k_cmfma<0><<<cgrid, 256, 0, stream>>>(XB, WPa + 1 * 36864, ST, nullptr, nullptr, nullptr, nullptr, XA);
    k_stats<<<256, 256, 0, stream>>>(XA, PART);
    k_finalize<<<1, 256, 0, stream>>>(PART, gs + 64, bes + 64, ST);
    // conv4: XA -> XB (raw y4)
    k_cmfma<0><<<cgrid, 256, 0, stream>>>(XA, WPa + 2 * 36864, ST, nullptr, nullptr, nullptr, nullptr, XB);
    k_stats<<<256, 256, 0, stream>>>(XB, PART);
    k_finalize<<<1, 256, 0, stream>>>(PART, gs + 128, bes + 128, ST);
    // watermark deltas from y4 ch0
    k_wmG<<<dim3(8, 8), 256, 0, stream>>>(XB, ST, TW, G);
    k_wmC<<<8, 256, 0, stream>>>(G, message, TW, DLT);
    // conv5 (enc staged from y4 + corr; img; msg via M term) -> XA
    k_cmfma<1><<<cgrid, 256, 0, stream>>>(XB, WP5, ST, image, DLT, TW, Mt, XA);
    k_stats<<<256, 256, 0, stream>>>(XA, PART);
    k_finalize<<<1, 256, 0, stream>>>(PART, acg, acbe, ST);
    // final 1x1 conv
    k_final<<<2048, 256, 0, stream>>>(XA, ST, fw, fb, out);
}